// Round 1
// baseline (4955.051 us; speedup 1.0000x reference)
//
#include <hip/hip_runtime.h>
#include <math.h>

#define N_U 100000
#define N_I 50000
#define DD 64
#define NQ 5
#define NNZ_N 1000000
#define NB 512
#define IN_DIM 768
#define TEMP 0.2f
// (1/TEMP) * log2(e)
#define SCALE2 7.2134752044448169f

__device__ __forceinline__ float wave_red_sum(float v) {
#pragma unroll
  for (int m = 32; m >= 1; m >>= 1) v += __shfl_xor(v, m, 64);
  return v;
}

// One nnz handled by 16 lanes (4 dims each, float4 gather, 8 scalar atomics).
__global__ void spmm_atomic(const int* __restrict__ rows, const int* __restrict__ cols,
                            const float* __restrict__ vals,
                            const float* __restrict__ srcU, const float* __restrict__ srcI,
                            float* __restrict__ dstU, float* __restrict__ dstI) {
  int gid = blockIdx.x * 256 + threadIdx.x;
  if (gid >= NNZ_N * 16) return;
  int e = gid >> 4;
  int q = (gid & 15) << 2;
  int r = rows[e], c = cols[e];
  float v = vals[e];
  float4 ei = *(const float4*)(srcI + (size_t)c * DD + q);
  float* du = dstU + (size_t)r * DD + q;
  atomicAdd(du + 0, v * ei.x);
  atomicAdd(du + 1, v * ei.y);
  atomicAdd(du + 2, v * ei.z);
  atomicAdd(du + 3, v * ei.w);
  float4 eu = *(const float4*)(srcU + (size_t)r * DD + q);
  float* di = dstI + (size_t)c * DD + q;
  atomicAdd(di + 0, v * eu.x);
  atomicAdd(di + 1, v * eu.y);
  atomicAdd(di + 2, v * eu.z);
  atomicAdd(di + 3, v * eu.w);
}

__global__ void add2_kernel(const float* __restrict__ a, const float* __restrict__ b,
                            float* __restrict__ o, int n) {
  int i = blockIdx.x * 256 + threadIdx.x;
  if (i < n) o[i] = a[i] + b[i];
}

// T[q][d] = sum_j vt[q*N+j] * Ep[j*64+d]   (Q=5, D=64)
__global__ void calcT_kernel(const float* __restrict__ vt, const float* __restrict__ Ep,
                             float* __restrict__ T, int N) {
  int lane = threadIdx.x & 63;
  int wave = (blockIdx.x * blockDim.x + threadIdx.x) >> 6;
  int nw = (gridDim.x * blockDim.x) >> 6;
  float a0 = 0.f, a1 = 0.f, a2 = 0.f, a3 = 0.f, a4 = 0.f;
  for (int j = wave; j < N; j += nw) {
    float x = Ep[(size_t)j * DD + lane];
    a0 += vt[0 * N + j] * x;
    a1 += vt[1 * N + j] * x;
    a2 += vt[2 * N + j] * x;
    a3 += vt[3 * N + j] * x;
    a4 += vt[4 * N + j] * x;
  }
  atomicAdd(&T[0 * DD + lane], a0);
  atomicAdd(&T[1 * DD + lane], a1);
  atomicAdd(&T[2 * DD + lane], a2);
  atomicAdd(&T[3 * DD + lane], a3);
  atomicAdd(&T[4 * DD + lane], a4);
}

// Gb rows: [0,512)=G_u[uids], [512,1024)=G_i[pos], [1024,1536)=G_i[neg]
__global__ void calcG_kernel(const int* __restrict__ uids, const int* __restrict__ pos,
                             const int* __restrict__ neg,
                             const float* __restrict__ Eu0, const float* __restrict__ Ei0,
                             const float* __restrict__ umuls, const float* __restrict__ vmuls,
                             const float* __restrict__ Ti, const float* __restrict__ Tu,
                             float* __restrict__ Gb) {
  int gid = blockIdx.x * 256 + threadIdx.x;
  if (gid >= 1536 * DD) return;
  int rrow = gid >> 6, d = gid & 63;
  float g;
  if (rrow < 512) {
    int u = uids[rrow];
    g = Eu0[(size_t)u * DD + d];
#pragma unroll
    for (int q = 0; q < NQ; q++) g += umuls[u * NQ + q] * Ti[q * DD + d];
  } else {
    int rr = rrow - 512;
    int i = (rr < 512) ? pos[rr] : neg[rr - 512];
    g = Ei0[(size_t)i * DD + d];
#pragma unroll
    for (int q = 0; q < NQ; q++) g += vmuls[i * NQ + q] * Tu[q * DD + d];
  }
  Gb[gid] = g;
}

// s_out[g] = sum_j exp(dot(G[g], E[j]) / TEMP); 2 g-rows per thread, E tiled in LDS.
#define TJ 256
__global__ void logits_kernel(const float* __restrict__ Gb, const float* __restrict__ E,
                              int N, float* __restrict__ s_out) {
  __shared__ __align__(16) float Et[TJ * DD];
  int tid = threadIdx.x;
  const float* G0 = Gb + (size_t)blockIdx.y * 512 * DD;
  float g0[DD], g1[DD];
#pragma unroll
  for (int k = 0; k < 16; k++) {
    float4 a = *(const float4*)(G0 + (size_t)tid * DD + k * 4);
    g0[k * 4 + 0] = a.x; g0[k * 4 + 1] = a.y; g0[k * 4 + 2] = a.z; g0[k * 4 + 3] = a.w;
    float4 b = *(const float4*)(G0 + (size_t)(tid + 256) * DD + k * 4);
    g1[k * 4 + 0] = b.x; g1[k * 4 + 1] = b.y; g1[k * 4 + 2] = b.z; g1[k * 4 + 3] = b.w;
  }
  int j0 = blockIdx.x * TJ;
  int jn = N - j0; if (jn > TJ) jn = TJ;
  for (int t = tid; t < jn * DD; t += 256) Et[t] = E[(size_t)j0 * DD + t];
  __syncthreads();
  float s0 = 0.f, s1 = 0.f;
  for (int j = 0; j < jn; j++) {
    float d0 = 0.f, d1 = 0.f;
#pragma unroll
    for (int k = 0; k < 16; k++) {
      float4 e = *(const float4*)(&Et[j * DD + k * 4]);
      d0 += g0[k * 4 + 0] * e.x + g0[k * 4 + 1] * e.y + g0[k * 4 + 2] * e.z + g0[k * 4 + 3] * e.w;
      d1 += g1[k * 4 + 0] * e.x + g1[k * 4 + 1] * e.y + g1[k * 4 + 2] * e.z + g1[k * 4 + 3] * e.w;
    }
    s0 += exp2f(d0 * SCALE2);
    s1 += exp2f(d1 * SCALE2);
  }
  atomicAdd(&s_out[blockIdx.y * 512 + tid], s0);
  atomicAdd(&s_out[blockIdx.y * 512 + tid + 256], s1);
}

// acc[0]=sum clip(posdot_u), acc[1]=sum clip(posdot_i), acc[2]=sum log_sigmoid(bpr)
__global__ void small_losses_kernel(const int* __restrict__ uids, const int* __restrict__ pos,
                                    const int* __restrict__ neg, const float* __restrict__ Gb,
                                    const float* __restrict__ Eu, const float* __restrict__ Ei,
                                    float* __restrict__ acc) {
  int wid = (blockIdx.x * 256 + threadIdx.x) >> 6;
  int lane = threadIdx.x & 63;
  if (wid >= 2048) return;
  if (wid < 512) {
    int u = uids[wid];
    float p = Gb[(size_t)wid * DD + lane] * Eu[(size_t)u * DD + lane];
    p = wave_red_sum(p);
    if (lane == 0) atomicAdd(&acc[0], fminf(fmaxf(p * (1.0f / TEMP), -5.0f), 5.0f));
  } else if (wid < 1536) {
    int r = wid - 512;
    int i = (r < 512) ? pos[r] : neg[r - 512];
    float p = Gb[(size_t)wid * DD + lane] * Ei[(size_t)i * DD + lane];
    p = wave_red_sum(p);
    if (lane == 0) atomicAdd(&acc[1], fminf(fmaxf(p * (1.0f / TEMP), -5.0f), 5.0f));
  } else {
    int b = wid - 1536;
    int u = uids[b], ip = pos[b], in2 = neg[b];
    float eu = Eu[(size_t)u * DD + lane];
    float sp = wave_red_sum(eu * Ei[(size_t)ip * DD + lane]);
    float sn = wave_red_sum(eu * Ei[(size_t)in2 * DD + lane]);
    if (lane == 0) {
      float x = sp - sn;
      float ls = fminf(x, 0.0f) - log1pf(expf(-fabsf(x)));
      atomicAdd(&acc[2], ls);
    }
  }
}

__global__ void sq_kernel(const float* __restrict__ p0, const float* __restrict__ p1,
                          const float* __restrict__ p2, const float* __restrict__ p3,
                          const float* __restrict__ p4, const float* __restrict__ p5,
                          float* __restrict__ acc) {
  const int n0 = N_U * DD, n1 = N_I * DD, n2 = IN_DIM * DD, n3 = DD, n4 = IN_DIM * DD, n5 = DD;
  const int total = n0 + n1 + n2 + n3 + n4 + n5;
  float s = 0.f;
  for (int i = blockIdx.x * blockDim.x + threadIdx.x; i < total; i += gridDim.x * blockDim.x) {
    int k = i; float v;
    if (k < n0) v = p0[k];
    else { k -= n0; if (k < n1) v = p1[k];
      else { k -= n1; if (k < n2) v = p2[k];
        else { k -= n2; if (k < n3) v = p3[k];
          else { k -= n3; if (k < n4) v = p4[k];
            else { k -= n4; v = p5[k]; } } } } }
    s += v * v;
  }
  s = wave_red_sum(s);
  __shared__ float sw[4];
  int lane = threadIdx.x & 63, w = threadIdx.x >> 6;
  if (lane == 0) sw[w] = s;
  __syncthreads();
  if (threadIdx.x == 0) atomicAdd(acc, sw[0] + sw[1] + sw[2] + sw[3]);
}

__global__ void extra_kernel(const int* __restrict__ unpop, const int* __restrict__ pop,
                             const float* __restrict__ Ei, float* __restrict__ acc) {
  int blk = blockIdx.x;        // 64 user-rows
  int t = threadIdx.x;         // 256 = 8 unpop x 32 pop
  int q = t >> 5, p = t & 31;
  int ui = unpop[blk * 8 + q];
  int pi = pop[blk * 32 + p];
  float s = 0.f;
#pragma unroll
  for (int d = 0; d < DD; d++) {
    float df = Ei[(size_t)ui * DD + d] - Ei[(size_t)pi * DD + d];
    s += df * df;
  }
  float dist = sqrtf(s);
  dist = wave_red_sum(dist);
  __shared__ float sw[4];
  int lane = t & 63, w = t >> 6;
  if (lane == 0) sw[w] = dist;
  __syncthreads();
  if (t == 0) atomicAdd(acc, (sw[0] + sw[1] + sw[2] + sw[3]) * (1.0f / 32.0f));
}

__global__ void finalize_kernel(const float* __restrict__ s_u, const float* __restrict__ s_i,
                                const float* __restrict__ acc, float* __restrict__ out) {
  int tid = threadIdx.x;  // 1024
  float lu = (tid < 512) ? logf(s_u[tid] + 1e-8f) : 0.f;
  float li = logf(s_i[tid] + 1e-8f);
  lu = wave_red_sum(lu);
  li = wave_red_sum(li);
  __shared__ float sa[16], sb[16];
  int lane = tid & 63, w = tid >> 6;
  if (lane == 0) { sa[w] = lu; sb[w] = li; }
  __syncthreads();
  if (tid == 0) {
    float su = 0.f, si = 0.f;
    for (int k = 0; k < 16; k++) { su += sa[k]; si += sb[k]; }
    float neg_score = su / 512.0f + si / 1024.0f;
    float pos_score = acc[0] / 512.0f + acc[1] / 1024.0f;
    float loss_s = neg_score - pos_score;
    float loss_r = -acc[2] / 512.0f;
    float loss_reg = 1e-7f * acc[3];
    float extra = acc[4];
    float loss = loss_r + 0.2f * loss_s + loss_reg + 0.01f * extra;
    out[0] = loss;
    out[1] = loss_r;
    out[2] = 0.2f * loss_s;
  }
}

__global__ void copy3_kernel(const float* __restrict__ m, const float* __restrict__ pa,
                             const float* __restrict__ na, float* __restrict__ out) {
  int i = blockIdx.x * 256 + threadIdx.x;
  if (i < NB * IN_DIM) {
    out[3 + i] = m[i];
    out[3 + NB * IN_DIM + i] = pa[i];
    out[3 + 2 * NB * IN_DIM + i] = na[i];
  }
}

extern "C" void kernel_launch(void* const* d_in, const int* in_sizes, int n_in,
                              void* d_out, int out_size, void* d_ws, size_t ws_size,
                              hipStream_t stream) {
  const int*   uids     = (const int*)d_in[0];
  const int*   pos      = (const int*)d_in[1];
  const int*   neg      = (const int*)d_in[2];
  const int*   adj_rows = (const int*)d_in[3];
  const int*   adj_cols = (const int*)d_in[4];
  const float* adj_vals = (const float*)d_in[5];
  const float* Eu0      = (const float*)d_in[6];
  const float* Ei0      = (const float*)d_in[7];
  const float* umuls    = (const float*)d_in[8];
  const float* vt       = (const float*)d_in[9];
  const float* vmuls    = (const float*)d_in[10];
  const float* ut       = (const float*)d_in[11];
  const float* W_api    = (const float*)d_in[12];
  const float* b_api    = (const float*)d_in[13];
  const float* W_mash   = (const float*)d_in[14];
  const float* b_mash   = (const float*)d_in[15];
  const float* pos_api  = (const float*)d_in[16];
  const float* neg_api  = (const float*)d_in[17];
  const float* mashup   = (const float*)d_in[18];
  const int*   unpop    = (const int*)d_in[19];
  const int*   popi     = (const int*)d_in[20];

  float* out = (float*)d_out;
  float* ws  = (float*)d_ws;

  // ws layout (floats)
  float* Z_u1 = ws;                 // 6,400,000
  float* Z_i1 = ws + 6400000;       // 3,200,000
  float* T_i  = ws + 9600000;       // 320
  float* T_u  = ws + 9600320;       // 320
  float* Gb   = ws + 9600640;       // 1536*64
  float* s_u  = ws + 9698944;       // 512
  float* s_i  = ws + 9699456;       // 1024
  float* acc  = ws + 9700480;       // 8

  // out layout: [0]=loss [1]=loss_r [2]=L1*loss_s [3..]=mashup,pos_api,neg_api then E_u,E_i
  float* Eu_out = out + 1179651;
  float* Ei_out = out + 7579651;

  hipMemsetAsync(d_ws, 0, 9700488ull * 4ull, stream);

  // layer 1: Z_u1 = A @ E_i0 ; Z_i1 = A^T @ E_u0
  spmm_atomic<<<62500, 256, 0, stream>>>(adj_rows, adj_cols, adj_vals, Eu0, Ei0, Z_u1, Z_i1);
  // partial sums E_*_out = E_*_0 + Z_*1 (also the input to the T reductions)
  add2_kernel<<<25000, 256, 0, stream>>>(Eu0, Z_u1, Eu_out, N_U * DD);
  add2_kernel<<<12500, 256, 0, stream>>>(Ei0, Z_i1, Ei_out, N_I * DD);
  // T_i = vt @ (E_i0+Z_i1), T_u = ut @ (E_u0+Z_u1)
  calcT_kernel<<<256, 256, 0, stream>>>(vt, Ei_out, T_i, N_I);
  calcT_kernel<<<256, 256, 0, stream>>>(ut, Eu_out, T_u, N_U);
  // G rows only at the 1536 sampled indices
  calcG_kernel<<<384, 256, 0, stream>>>(uids, pos, neg, Eu0, Ei0, umuls, vmuls, T_i, T_u, Gb);
  // layer 2: E_*_out += A(^T) @ Z_*1  -> final E_u, E_i directly in d_out
  spmm_atomic<<<62500, 256, 0, stream>>>(adj_rows, adj_cols, adj_vals, Z_u1, Z_i1, Eu_out, Ei_out);
  // contrastive exp-sums
  logits_kernel<<<dim3((N_U + TJ - 1) / TJ, 1), 256, 0, stream>>>(Gb, Eu_out, N_U, s_u);
  logits_kernel<<<dim3((N_I + TJ - 1) / TJ, 2), 256, 0, stream>>>(Gb + 512 * DD, Ei_out, N_I, s_i);
  // pos-scores + BPR
  small_losses_kernel<<<512, 256, 0, stream>>>(uids, pos, neg, Gb, Eu_out, Ei_out, acc);
  // L2 reg
  sq_kernel<<<1024, 256, 0, stream>>>(Eu0, Ei0, W_api, b_api, W_mash, b_mash, acc + 3);
  // popular/unpopular distances
  extra_kernel<<<64, 256, 0, stream>>>(unpop, popi, Ei_out, acc + 4);
  // scalars
  finalize_kernel<<<1, 1024, 0, stream>>>(s_u, s_i, acc, out);
  // passthrough embeddings
  copy3_kernel<<<1536, 256, 0, stream>>>(mashup, pos_api, neg_api, out);
  (void)in_sizes; (void)n_in; (void)out_size; (void)ws_size;
}

// Round 2
// 1873.250 us; speedup vs baseline: 2.6452x; 2.6452x over previous
//
#include <hip/hip_runtime.h>
#include <math.h>

#define N_U 100000
#define N_I 50000
#define DD 64
#define NQ 5
#define NNZ_N 1000000
#define NB 512
#define IN_DIM 768
#define TEMP 0.2f
// (1/TEMP) * log2(e)
#define SCALE2 7.2134752044448169f

// ws dword offsets
#define WS_ZI1   0          // 3,200,000 f  (Z_i1)
#define WS_CNT   3200000    // 150,001 int
#define WS_OFFS  3350016    // 150,001 int
#define WS_CUR   3500032    // 150,000 int
#define WS_BSUM  3650048    // 256 int
#define WS_PAIRS 3650304    // 4,000,000 dwords (2M int2)
#define WS_TI    7650304    // 320 f
#define WS_TU    7650624    // 320 f
#define WS_GB    7650944    // 98,304 f
#define WS_SU    7749248    // 512 f
#define WS_SI    7749760    // 1024 f
#define WS_ACC   7750784    // 8 f
#define WS_SMALL_LEN (7750792 - WS_TI)

__device__ __forceinline__ float wave_red_sum(float v) {
#pragma unroll
  for (int m = 32; m >= 1; m >>= 1) v += __shfl_xor(v, m, 64);
  return v;
}

// ---------------- CSR/CSC build ----------------

__global__ void hist_kernel(const int* __restrict__ rows, const int* __restrict__ cols,
                            int* __restrict__ counts) {
  int e = blockIdx.x * 256 + threadIdx.x;
  if (e >= NNZ_N) return;
  atomicAdd(&counts[rows[e]], 1);
  atomicAdd(&counts[N_U + cols[e]], 1);
}

// block of 256 threads x 4 elems = 1024 per block
__global__ void scan1_kernel(const int* __restrict__ counts, int* __restrict__ bsum, int n) {
  int t = threadIdx.x;
  int base = blockIdx.x * 1024 + t * 4;
  int s = 0;
#pragma unroll
  for (int k = 0; k < 4; k++) { int i = base + k; if (i < n) s += counts[i]; }
#pragma unroll
  for (int m = 32; m >= 1; m >>= 1) s += __shfl_xor(s, m, 64);
  __shared__ int sw[4];
  if ((t & 63) == 0) sw[t >> 6] = s;
  __syncthreads();
  if (t == 0) bsum[blockIdx.x] = sw[0] + sw[1] + sw[2] + sw[3];
}

// single block, exclusive scan of nb (<256) block sums in place
__global__ void scan2_kernel(int* __restrict__ bsum, int nb) {
  int t = threadIdx.x;
  int lane = t & 63, w = t >> 6;
  int orig = (t < nb) ? bsum[t] : 0;
  int v = orig;
#pragma unroll
  for (int m = 1; m < 64; m <<= 1) { int o = __shfl_up(v, m, 64); if (lane >= m) v += o; }
  __shared__ int wt[4];
  if (lane == 63) wt[w] = v;
  __syncthreads();
  int add = 0;
  for (int k = 0; k < w; k++) add += wt[k];
  if (t < nb) bsum[t] = v - orig + add;
}

__global__ void scan3_kernel(const int* __restrict__ counts, const int* __restrict__ bsum,
                             int* __restrict__ offs, int* __restrict__ cursor, int n) {
  int t = threadIdx.x;
  int lane = t & 63, w = t >> 6;
  int base = blockIdx.x * 1024 + t * 4;
  int c[4];
  int s = 0;
#pragma unroll
  for (int k = 0; k < 4; k++) { int i = base + k; c[k] = (i < n) ? counts[i] : 0; s += c[k]; }
  int v = s;
#pragma unroll
  for (int m = 1; m < 64; m <<= 1) { int o = __shfl_up(v, m, 64); if (lane >= m) v += o; }
  __shared__ int wt[4];
  if (lane == 63) wt[w] = v;
  __syncthreads();
  int add = bsum[blockIdx.x];
  for (int k = 0; k < w; k++) add += wt[k];
  int excl = add + v - s;
#pragma unroll
  for (int k = 0; k < 4; k++) {
    int i = base + k;
    if (i < n) {
      offs[i] = excl;
      cursor[i] = excl;
      if (i == n - 1) offs[n] = excl + c[k];
      excl += c[k];
    }
  }
}

__global__ void scatter_kernel(const int* __restrict__ rows, const int* __restrict__ cols,
                               const float* __restrict__ vals, int* __restrict__ cursor,
                               int2* __restrict__ pairs) {
  int e = blockIdx.x * 256 + threadIdx.x;
  if (e >= NNZ_N) return;
  int r = rows[e], c = cols[e];
  int vb = __float_as_int(vals[e]);
  int s1 = atomicAdd(&cursor[r], 1);
  pairs[s1] = make_int2(c, vb);
  int s2 = atomicAdd(&cursor[N_U + c], 1);
  pairs[s2] = make_int2(r, vb);
}

// dst[row] = (base0?base0[row]:0) + (base1?base1[row]:0) + sum_k val_k * src[idx_k]
// one wave per row, lane = dim. base1 may alias dst (read-before-write per lane).
__global__ void spmm_gather(const int* __restrict__ offs, const int2* __restrict__ pairs,
                            const float* __restrict__ src, const float* __restrict__ base0,
                            const float* __restrict__ base1, float* __restrict__ dst,
                            int n_rows) {
  int gid = blockIdx.x * 256 + threadIdx.x;
  int row = gid >> 6, lane = gid & 63;
  if (row >= n_rows) return;
  int s = offs[row], e = offs[row + 1];
  float acc = 0.f;
  for (int k = s; k < e; k++) {
    int2 p = pairs[k];
    acc += __int_as_float(p.y) * src[(size_t)p.x * DD + lane];
  }
  if (base0) acc += base0[(size_t)row * DD + lane];
  if (base1) acc += base1[(size_t)row * DD + lane];
  dst[(size_t)row * DD + lane] = acc;
}

// ---------------- SVD low-rank path ----------------

// T[q][d] = sum_j vt[q*N+j] * (A[j*64+d] + B[j*64+d])
__global__ void calcT_kernel(const float* __restrict__ vt, const float* __restrict__ A,
                             const float* __restrict__ B, float* __restrict__ T, int N) {
  int lane = threadIdx.x & 63;
  int wave = (blockIdx.x * blockDim.x + threadIdx.x) >> 6;
  int nw = (gridDim.x * blockDim.x) >> 6;
  float a0 = 0.f, a1 = 0.f, a2 = 0.f, a3 = 0.f, a4 = 0.f;
  for (int j = wave; j < N; j += nw) {
    float x = A[(size_t)j * DD + lane] + B[(size_t)j * DD + lane];
    a0 += vt[0 * N + j] * x;
    a1 += vt[1 * N + j] * x;
    a2 += vt[2 * N + j] * x;
    a3 += vt[3 * N + j] * x;
    a4 += vt[4 * N + j] * x;
  }
  atomicAdd(&T[0 * DD + lane], a0);
  atomicAdd(&T[1 * DD + lane], a1);
  atomicAdd(&T[2 * DD + lane], a2);
  atomicAdd(&T[3 * DD + lane], a3);
  atomicAdd(&T[4 * DD + lane], a4);
}

// Gb rows: [0,512)=G_u[uids], [512,1024)=G_i[pos], [1024,1536)=G_i[neg]
__global__ void calcG_kernel(const int* __restrict__ uids, const int* __restrict__ pos,
                             const int* __restrict__ neg,
                             const float* __restrict__ Eu0, const float* __restrict__ Ei0,
                             const float* __restrict__ umuls, const float* __restrict__ vmuls,
                             const float* __restrict__ Ti, const float* __restrict__ Tu,
                             float* __restrict__ Gb) {
  int gid = blockIdx.x * 256 + threadIdx.x;
  if (gid >= 1536 * DD) return;
  int rrow = gid >> 6, d = gid & 63;
  float g;
  if (rrow < 512) {
    int u = uids[rrow];
    g = Eu0[(size_t)u * DD + d];
#pragma unroll
    for (int q = 0; q < NQ; q++) g += umuls[u * NQ + q] * Ti[q * DD + d];
  } else {
    int rr = rrow - 512;
    int i = (rr < 512) ? pos[rr] : neg[rr - 512];
    g = Ei0[(size_t)i * DD + d];
#pragma unroll
    for (int q = 0; q < NQ; q++) g += vmuls[i * NQ + q] * Tu[q * DD + d];
  }
  Gb[gid] = g;
}

// ---------------- contrastive exp-sums ----------------

#define TJ 256
__global__ void logits_kernel(const float* __restrict__ Gb, const float* __restrict__ E,
                              int N, float* __restrict__ s_out) {
  __shared__ __align__(16) float Et[TJ * DD];
  int tid = threadIdx.x;
  const float* G0 = Gb + (size_t)blockIdx.y * 512 * DD;
  float g0[DD], g1[DD];
#pragma unroll
  for (int k = 0; k < 16; k++) {
    float4 a = *(const float4*)(G0 + (size_t)tid * DD + k * 4);
    g0[k * 4 + 0] = a.x; g0[k * 4 + 1] = a.y; g0[k * 4 + 2] = a.z; g0[k * 4 + 3] = a.w;
    float4 b = *(const float4*)(G0 + (size_t)(tid + 256) * DD + k * 4);
    g1[k * 4 + 0] = b.x; g1[k * 4 + 1] = b.y; g1[k * 4 + 2] = b.z; g1[k * 4 + 3] = b.w;
  }
  int j0 = blockIdx.x * TJ;
  int jn = N - j0; if (jn > TJ) jn = TJ;
  for (int t = tid; t < jn * DD; t += 256) Et[t] = E[(size_t)j0 * DD + t];
  __syncthreads();
  float s0 = 0.f, s1 = 0.f;
  for (int j = 0; j < jn; j++) {
    float d0 = 0.f, d1 = 0.f;
#pragma unroll
    for (int k = 0; k < 16; k++) {
      float4 e = *(const float4*)(&Et[j * DD + k * 4]);
      d0 += g0[k * 4 + 0] * e.x + g0[k * 4 + 1] * e.y + g0[k * 4 + 2] * e.z + g0[k * 4 + 3] * e.w;
      d1 += g1[k * 4 + 0] * e.x + g1[k * 4 + 1] * e.y + g1[k * 4 + 2] * e.z + g1[k * 4 + 3] * e.w;
    }
    s0 += exp2f(d0 * SCALE2);
    s1 += exp2f(d1 * SCALE2);
  }
  atomicAdd(&s_out[blockIdx.y * 512 + tid], s0);
  atomicAdd(&s_out[blockIdx.y * 512 + tid + 256], s1);
}

// ---------------- small losses ----------------

__global__ void small_losses_kernel(const int* __restrict__ uids, const int* __restrict__ pos,
                                    const int* __restrict__ neg, const float* __restrict__ Gb,
                                    const float* __restrict__ Eu, const float* __restrict__ Ei,
                                    float* __restrict__ acc) {
  int wid = (blockIdx.x * 256 + threadIdx.x) >> 6;
  int lane = threadIdx.x & 63;
  if (wid >= 2048) return;
  if (wid < 512) {
    int u = uids[wid];
    float p = Gb[(size_t)wid * DD + lane] * Eu[(size_t)u * DD + lane];
    p = wave_red_sum(p);
    if (lane == 0) atomicAdd(&acc[0], fminf(fmaxf(p * (1.0f / TEMP), -5.0f), 5.0f));
  } else if (wid < 1536) {
    int r = wid - 512;
    int i = (r < 512) ? pos[r] : neg[r - 512];
    float p = Gb[(size_t)wid * DD + lane] * Ei[(size_t)i * DD + lane];
    p = wave_red_sum(p);
    if (lane == 0) atomicAdd(&acc[1], fminf(fmaxf(p * (1.0f / TEMP), -5.0f), 5.0f));
  } else {
    int b = wid - 1536;
    int u = uids[b], ip = pos[b], in2 = neg[b];
    float eu = Eu[(size_t)u * DD + lane];
    float sp = wave_red_sum(eu * Ei[(size_t)ip * DD + lane]);
    float sn = wave_red_sum(eu * Ei[(size_t)in2 * DD + lane]);
    if (lane == 0) {
      float x = sp - sn;
      float ls = fminf(x, 0.0f) - log1pf(expf(-fabsf(x)));
      atomicAdd(&acc[2], ls);
    }
  }
}

__global__ void sq_kernel(const float* __restrict__ p0, const float* __restrict__ p1,
                          const float* __restrict__ p2, const float* __restrict__ p3,
                          const float* __restrict__ p4, const float* __restrict__ p5,
                          float* __restrict__ acc) {
  const int n0 = N_U * DD, n1 = N_I * DD, n2 = IN_DIM * DD, n3 = DD, n4 = IN_DIM * DD, n5 = DD;
  const int total = n0 + n1 + n2 + n3 + n4 + n5;
  float s = 0.f;
  for (int i = blockIdx.x * blockDim.x + threadIdx.x; i < total; i += gridDim.x * blockDim.x) {
    int k = i; float v;
    if (k < n0) v = p0[k];
    else { k -= n0; if (k < n1) v = p1[k];
      else { k -= n1; if (k < n2) v = p2[k];
        else { k -= n2; if (k < n3) v = p3[k];
          else { k -= n3; if (k < n4) v = p4[k];
            else { k -= n4; v = p5[k]; } } } } }
    s += v * v;
  }
  s = wave_red_sum(s);
  __shared__ float sw[4];
  int lane = threadIdx.x & 63, w = threadIdx.x >> 6;
  if (lane == 0) sw[w] = s;
  __syncthreads();
  if (threadIdx.x == 0) atomicAdd(acc, sw[0] + sw[1] + sw[2] + sw[3]);
}

__global__ void extra_kernel(const int* __restrict__ unpop, const int* __restrict__ pop,
                             const float* __restrict__ Ei, float* __restrict__ acc) {
  int blk = blockIdx.x;
  int t = threadIdx.x;
  int q = t >> 5, p = t & 31;
  int ui = unpop[blk * 8 + q];
  int pi = pop[blk * 32 + p];
  float s = 0.f;
#pragma unroll
  for (int d = 0; d < DD; d++) {
    float df = Ei[(size_t)ui * DD + d] - Ei[(size_t)pi * DD + d];
    s += df * df;
  }
  float dist = sqrtf(s);
  dist = wave_red_sum(dist);
  __shared__ float sw[4];
  int lane = t & 63, w = t >> 6;
  if (lane == 0) sw[w] = dist;
  __syncthreads();
  if (t == 0) atomicAdd(acc, (sw[0] + sw[1] + sw[2] + sw[3]) * (1.0f / 32.0f));
}

__global__ void finalize_kernel(const float* __restrict__ s_u, const float* __restrict__ s_i,
                                const float* __restrict__ acc, float* __restrict__ out) {
  int tid = threadIdx.x;  // 1024
  float lu = (tid < 512) ? logf(s_u[tid] + 1e-8f) : 0.f;
  float li = logf(s_i[tid] + 1e-8f);
  lu = wave_red_sum(lu);
  li = wave_red_sum(li);
  __shared__ float sa[16], sb[16];
  int lane = tid & 63, w = tid >> 6;
  if (lane == 0) { sa[w] = lu; sb[w] = li; }
  __syncthreads();
  if (tid == 0) {
    float su = 0.f, si = 0.f;
    for (int k = 0; k < 16; k++) { su += sa[k]; si += sb[k]; }
    float neg_score = su / 512.0f + si / 1024.0f;
    float pos_score = acc[0] / 512.0f + acc[1] / 1024.0f;
    float loss_s = neg_score - pos_score;
    float loss_r = -acc[2] / 512.0f;
    float loss_reg = 1e-7f * acc[3];
    float extra = acc[4];
    float loss = loss_r + 0.2f * loss_s + loss_reg + 0.01f * extra;
    out[0] = loss;
    out[1] = loss_r;
    out[2] = 0.2f * loss_s;
  }
}

__global__ void copy3_kernel(const float* __restrict__ m, const float* __restrict__ pa,
                             const float* __restrict__ na, float* __restrict__ out) {
  int i = blockIdx.x * 256 + threadIdx.x;
  if (i < NB * IN_DIM) {
    out[3 + i] = m[i];
    out[3 + NB * IN_DIM + i] = pa[i];
    out[3 + 2 * NB * IN_DIM + i] = na[i];
  }
}

extern "C" void kernel_launch(void* const* d_in, const int* in_sizes, int n_in,
                              void* d_out, int out_size, void* d_ws, size_t ws_size,
                              hipStream_t stream) {
  const int*   uids     = (const int*)d_in[0];
  const int*   pos      = (const int*)d_in[1];
  const int*   neg      = (const int*)d_in[2];
  const int*   adj_rows = (const int*)d_in[3];
  const int*   adj_cols = (const int*)d_in[4];
  const float* adj_vals = (const float*)d_in[5];
  const float* Eu0      = (const float*)d_in[6];
  const float* Ei0      = (const float*)d_in[7];
  const float* umuls    = (const float*)d_in[8];
  const float* vt       = (const float*)d_in[9];
  const float* vmuls    = (const float*)d_in[10];
  const float* ut       = (const float*)d_in[11];
  const float* W_api    = (const float*)d_in[12];
  const float* b_api    = (const float*)d_in[13];
  const float* W_mash   = (const float*)d_in[14];
  const float* b_mash   = (const float*)d_in[15];
  const float* pos_api  = (const float*)d_in[16];
  const float* neg_api  = (const float*)d_in[17];
  const float* mashup   = (const float*)d_in[18];
  const int*   unpop    = (const int*)d_in[19];
  const int*   popi     = (const int*)d_in[20];

  float* out = (float*)d_out;
  float* ws  = (float*)d_ws;
  int*   wsi = (int*)d_ws;

  float* Z_i1   = ws + WS_ZI1;
  int*   counts = wsi + WS_CNT;
  int*   offs   = wsi + WS_OFFS;
  int*   cursor = wsi + WS_CUR;
  int*   bsum   = wsi + WS_BSUM;
  int2*  pairs  = (int2*)(wsi + WS_PAIRS);
  float* T_i    = ws + WS_TI;
  float* T_u    = ws + WS_TU;
  float* Gb     = ws + WS_GB;
  float* s_u    = ws + WS_SU;
  float* s_i    = ws + WS_SI;
  float* acc    = ws + WS_ACC;

  // out layout: [0..3) scalars, then mashup/pos_api/neg_api, then E_u, E_i
  float* Eu_out = out + 1179651;   // also holds Z_u1 between layer 1 and layer 2
  float* Ei_out = out + 7579651;

  // zero the counters and the small accumulator region
  hipMemsetAsync(counts, 0, 150001ull * 4ull, stream);
  hipMemsetAsync(T_i, 0, (size_t)WS_SMALL_LEN * 4ull, stream);

  const int NROWS = N_U + N_I;            // 150000
  const int SCAN_BLKS = (NROWS + 1023) / 1024;  // 147

  // build CSR (u rows) + CSC (i rows) in one combined slot space [0, 2*NNZ)
  hist_kernel<<<(NNZ_N + 255) / 256, 256, 0, stream>>>(adj_rows, adj_cols, counts);
  scan1_kernel<<<SCAN_BLKS, 256, 0, stream>>>(counts, bsum, NROWS);
  scan2_kernel<<<1, 256, 0, stream>>>(bsum, SCAN_BLKS);
  scan3_kernel<<<SCAN_BLKS, 256, 0, stream>>>(counts, bsum, offs, cursor, NROWS);
  scatter_kernel<<<(NNZ_N + 255) / 256, 256, 0, stream>>>(adj_rows, adj_cols, adj_vals, cursor, pairs);

  // layer 1: Z_u1 = A @ Ei0 (stored in Eu_out), Z_i1 = A^T @ Eu0 (ws)
  spmm_gather<<<25000, 256, 0, stream>>>(offs, pairs, Ei0, nullptr, nullptr, Eu_out, N_U);
  spmm_gather<<<12500, 256, 0, stream>>>(offs + N_U, pairs, Eu0, nullptr, nullptr, Z_i1, N_I);

  // T_i = vt @ (Ei0 + Z_i1), T_u = ut @ (Eu0 + Z_u1)
  calcT_kernel<<<256, 256, 0, stream>>>(vt, Ei0, Z_i1, T_i, N_I);
  calcT_kernel<<<256, 256, 0, stream>>>(ut, Eu0, Eu_out, T_u, N_U);
  calcG_kernel<<<384, 256, 0, stream>>>(uids, pos, neg, Eu0, Ei0, umuls, vmuls, T_i, T_u, Gb);

  // layer 2 (i first: reads Z_u1 from Eu_out before it is overwritten)
  // Ei_out = Ei0 + Z_i1 + A^T @ Z_u1
  spmm_gather<<<12500, 256, 0, stream>>>(offs + N_U, pairs, Eu_out, Ei0, Z_i1, Ei_out, N_I);
  // Eu_out = Eu0 + Z_u1 + A @ Z_i1   (base1 aliases dst: read-before-write per lane)
  spmm_gather<<<25000, 256, 0, stream>>>(offs, pairs, Z_i1, Eu0, Eu_out, Eu_out, N_U);

  // contrastive exp-sums
  logits_kernel<<<dim3((N_U + TJ - 1) / TJ, 1), 256, 0, stream>>>(Gb, Eu_out, N_U, s_u);
  logits_kernel<<<dim3((N_I + TJ - 1) / TJ, 2), 256, 0, stream>>>(Gb + 512 * DD, Ei_out, N_I, s_i);

  small_losses_kernel<<<512, 256, 0, stream>>>(uids, pos, neg, Gb, Eu_out, Ei_out, acc);
  sq_kernel<<<1024, 256, 0, stream>>>(Eu0, Ei0, W_api, b_api, W_mash, b_mash, acc + 3);
  extra_kernel<<<64, 256, 0, stream>>>(unpop, popi, Ei_out, acc + 4);
  finalize_kernel<<<1, 1024, 0, stream>>>(s_u, s_i, acc, out);
  copy3_kernel<<<1536, 256, 0, stream>>>(mashup, pos_api, neg_api, out);
  (void)in_sizes; (void)n_in; (void)out_size; (void)ws_size;
}

// Round 3
// 1160.092 us; speedup vs baseline: 4.2713x; 1.6147x over previous
//
#include <hip/hip_runtime.h>
#include <math.h>

#define N_U 100000
#define N_I 50000
#define DD 64
#define NQ 5
#define NNZ_N 1000000
#define NB 512
#define IN_DIM 768
#define TEMP 0.2f
// (1/TEMP) * log2(e)
#define SCALE2 7.2134752044448169f

// ws dword offsets
#define WS_ZI1   0          // 3,200,000 f  (Z_i1)
#define WS_CNT   3200000    // 150,001 int
#define WS_OFFS  3350016    // 150,001 int
#define WS_CUR   3500032    // 150,000 int
#define WS_BSUM  3650048    // 256 int
#define WS_PAIRS 3650304    // 4,000,000 dwords (2M int2)
#define WS_TI    7650304    // 320 f
#define WS_TU    7650624    // 320 f
#define WS_GB    7650944    // 98,304 f
#define WS_SU    7749248    // 512 f
#define WS_SI    7749760    // 1024 f
#define WS_ACC   7750784    // 8 f
#define WS_SMALL_LEN (7750792 - WS_TI)

__device__ __forceinline__ float wave_red_sum(float v) {
#pragma unroll
  for (int m = 32; m >= 1; m >>= 1) v += __shfl_xor(v, m, 64);
  return v;
}

// ---------------- CSR/CSC build ----------------

__global__ void hist_kernel(const int* __restrict__ rows, const int* __restrict__ cols,
                            int* __restrict__ counts) {
  int e = blockIdx.x * 256 + threadIdx.x;
  if (e >= NNZ_N) return;
  atomicAdd(&counts[rows[e]], 1);
  atomicAdd(&counts[N_U + cols[e]], 1);
}

__global__ void scan1_kernel(const int* __restrict__ counts, int* __restrict__ bsum, int n) {
  int t = threadIdx.x;
  int base = blockIdx.x * 1024 + t * 4;
  int s = 0;
#pragma unroll
  for (int k = 0; k < 4; k++) { int i = base + k; if (i < n) s += counts[i]; }
#pragma unroll
  for (int m = 32; m >= 1; m >>= 1) s += __shfl_xor(s, m, 64);
  __shared__ int sw[4];
  if ((t & 63) == 0) sw[t >> 6] = s;
  __syncthreads();
  if (t == 0) bsum[blockIdx.x] = sw[0] + sw[1] + sw[2] + sw[3];
}

__global__ void scan2_kernel(int* __restrict__ bsum, int nb) {
  int t = threadIdx.x;
  int lane = t & 63, w = t >> 6;
  int orig = (t < nb) ? bsum[t] : 0;
  int v = orig;
#pragma unroll
  for (int m = 1; m < 64; m <<= 1) { int o = __shfl_up(v, m, 64); if (lane >= m) v += o; }
  __shared__ int wt[4];
  if (lane == 63) wt[w] = v;
  __syncthreads();
  int add = 0;
  for (int k = 0; k < w; k++) add += wt[k];
  if (t < nb) bsum[t] = v - orig + add;
}

__global__ void scan3_kernel(const int* __restrict__ counts, const int* __restrict__ bsum,
                             int* __restrict__ offs, int* __restrict__ cursor, int n) {
  int t = threadIdx.x;
  int lane = t & 63, w = t >> 6;
  int base = blockIdx.x * 1024 + t * 4;
  int c[4];
  int s = 0;
#pragma unroll
  for (int k = 0; k < 4; k++) { int i = base + k; c[k] = (i < n) ? counts[i] : 0; s += c[k]; }
  int v = s;
#pragma unroll
  for (int m = 1; m < 64; m <<= 1) { int o = __shfl_up(v, m, 64); if (lane >= m) v += o; }
  __shared__ int wt[4];
  if (lane == 63) wt[w] = v;
  __syncthreads();
  int add = bsum[blockIdx.x];
  for (int k = 0; k < w; k++) add += wt[k];
  int excl = add + v - s;
#pragma unroll
  for (int k = 0; k < 4; k++) {
    int i = base + k;
    if (i < n) {
      offs[i] = excl;
      cursor[i] = excl;
      if (i == n - 1) offs[n] = excl + c[k];
      excl += c[k];
    }
  }
}

__global__ void scatter_kernel(const int* __restrict__ rows, const int* __restrict__ cols,
                               const float* __restrict__ vals, int* __restrict__ cursor,
                               int2* __restrict__ pairs) {
  int e = blockIdx.x * 256 + threadIdx.x;
  if (e >= NNZ_N) return;
  int r = rows[e], c = cols[e];
  int vb = __float_as_int(vals[e]);
  int s1 = atomicAdd(&cursor[r], 1);
  pairs[s1] = make_int2(c, vb);
  int s2 = atomicAdd(&cursor[N_U + c], 1);
  pairs[s2] = make_int2(r, vb);
}

// dst[row] = (base0?base0[row]:0) + (base1?base1[row]:0) + sum_k val_k * src[idx_k]
__global__ void spmm_gather(const int* __restrict__ offs, const int2* __restrict__ pairs,
                            const float* __restrict__ src, const float* __restrict__ base0,
                            const float* __restrict__ base1, float* __restrict__ dst,
                            int n_rows) {
  int gid = blockIdx.x * 256 + threadIdx.x;
  int row = gid >> 6, lane = gid & 63;
  if (row >= n_rows) return;
  int s = offs[row], e = offs[row + 1];
  float acc = 0.f;
  for (int k = s; k < e; k++) {
    int2 p = pairs[k];
    acc += __int_as_float(p.y) * src[(size_t)p.x * DD + lane];
  }
  if (base0) acc += base0[(size_t)row * DD + lane];
  if (base1) acc += base1[(size_t)row * DD + lane];
  dst[(size_t)row * DD + lane] = acc;
}

// ---------------- SVD low-rank path ----------------

__global__ void calcT_kernel(const float* __restrict__ vt, const float* __restrict__ A,
                             const float* __restrict__ B, float* __restrict__ T, int N) {
  int lane = threadIdx.x & 63;
  int wave = (blockIdx.x * blockDim.x + threadIdx.x) >> 6;
  int nw = (gridDim.x * blockDim.x) >> 6;
  float a0 = 0.f, a1 = 0.f, a2 = 0.f, a3 = 0.f, a4 = 0.f;
  for (int j = wave; j < N; j += nw) {
    float x = A[(size_t)j * DD + lane] + B[(size_t)j * DD + lane];
    a0 += vt[0 * N + j] * x;
    a1 += vt[1 * N + j] * x;
    a2 += vt[2 * N + j] * x;
    a3 += vt[3 * N + j] * x;
    a4 += vt[4 * N + j] * x;
  }
  atomicAdd(&T[0 * DD + lane], a0);
  atomicAdd(&T[1 * DD + lane], a1);
  atomicAdd(&T[2 * DD + lane], a2);
  atomicAdd(&T[3 * DD + lane], a3);
  atomicAdd(&T[4 * DD + lane], a4);
}

__global__ void calcG_kernel(const int* __restrict__ uids, const int* __restrict__ pos,
                             const int* __restrict__ neg,
                             const float* __restrict__ Eu0, const float* __restrict__ Ei0,
                             const float* __restrict__ umuls, const float* __restrict__ vmuls,
                             const float* __restrict__ Ti, const float* __restrict__ Tu,
                             float* __restrict__ Gb) {
  int gid = blockIdx.x * 256 + threadIdx.x;
  if (gid >= 1536 * DD) return;
  int rrow = gid >> 6, d = gid & 63;
  float g;
  if (rrow < 512) {
    int u = uids[rrow];
    g = Eu0[(size_t)u * DD + d];
#pragma unroll
    for (int q = 0; q < NQ; q++) g += umuls[u * NQ + q] * Ti[q * DD + d];
  } else {
    int rr = rrow - 512;
    int i = (rr < 512) ? pos[rr] : neg[rr - 512];
    g = Ei0[(size_t)i * DD + d];
#pragma unroll
    for (int q = 0; q < NQ; q++) g += vmuls[i * NQ + q] * Tu[q * DD + d];
  }
  Gb[gid] = g;
}

// ---------------- contrastive exp-sums (register-blocked GEMM style) ----------------
// block: 128 g-rows x 128 j's; thread: 8x8; K staged in 4 chunks of 16 (d-major LDS)
__global__ __launch_bounds__(256) void logits_kernel(
    const float* __restrict__ Gb, const float* __restrict__ E,
    int N, float* __restrict__ s_out) {
  __shared__ float smem[4096];  // Gs [16][128] | Es [16][128]; reused as red[128][17]
  float* Gs = smem;
  float* Es = smem + 2048;

  int tid = threadIdx.x;
  int tr = tid >> 4;      // 0..15 g-group
  int tc = tid & 15;      // 0..15 j-group
  int g0 = blockIdx.y * 128;
  int j0 = blockIdx.x * 128;

  float acc[8][8];
#pragma unroll
  for (int i = 0; i < 8; i++)
#pragma unroll
    for (int j = 0; j < 8; j++) acc[i][j] = 0.f;

  int sr = tid >> 1;      // staging row 0..127
  int dh = tid & 1;       // staging d-half

  for (int dc = 0; dc < 4; dc++) {
    if (dc) __syncthreads();
    // stage G chunk: Gs[d][g] = Gb[(g0+g)*64 + dc*16 + d]
    {
      const float* p = Gb + (size_t)(g0 + sr) * DD + dc * 16 + dh * 8;
      float4 x = *(const float4*)p;
      float4 y = *(const float4*)(p + 4);
      int db = dh * 8;
      Gs[(db + 0) * 128 + sr] = x.x; Gs[(db + 1) * 128 + sr] = x.y;
      Gs[(db + 2) * 128 + sr] = x.z; Gs[(db + 3) * 128 + sr] = x.w;
      Gs[(db + 4) * 128 + sr] = y.x; Gs[(db + 5) * 128 + sr] = y.y;
      Gs[(db + 6) * 128 + sr] = y.z; Gs[(db + 7) * 128 + sr] = y.w;
    }
    // stage E chunk (guarded): Es[d][j] = E[(j0+j)*64 + dc*16 + d]
    {
      float4 x = make_float4(0.f, 0.f, 0.f, 0.f), y = x;
      if (j0 + sr < N) {
        const float* q = E + (size_t)(j0 + sr) * DD + dc * 16 + dh * 8;
        x = *(const float4*)q;
        y = *(const float4*)(q + 4);
      }
      int db = dh * 8;
      Es[(db + 0) * 128 + sr] = x.x; Es[(db + 1) * 128 + sr] = x.y;
      Es[(db + 2) * 128 + sr] = x.z; Es[(db + 3) * 128 + sr] = x.w;
      Es[(db + 4) * 128 + sr] = y.x; Es[(db + 5) * 128 + sr] = y.y;
      Es[(db + 6) * 128 + sr] = y.z; Es[(db + 7) * 128 + sr] = y.w;
    }
    __syncthreads();
#pragma unroll
    for (int d = 0; d < 16; d++) {
      float4 a0 = *(const float4*)&Gs[d * 128 + tr * 8];
      float4 a1 = *(const float4*)&Gs[d * 128 + tr * 8 + 4];
      float4 b0 = *(const float4*)&Es[d * 128 + tc * 8];
      float4 b1 = *(const float4*)&Es[d * 128 + tc * 8 + 4];
      float av[8] = {a0.x, a0.y, a0.z, a0.w, a1.x, a1.y, a1.z, a1.w};
      float bv[8] = {b0.x, b0.y, b0.z, b0.w, b1.x, b1.y, b1.z, b1.w};
#pragma unroll
      for (int i = 0; i < 8; i++)
#pragma unroll
        for (int j = 0; j < 8; j++) acc[i][j] += av[i] * bv[j];
    }
  }

  // exp + per-thread partial over this thread's 8 j's
  float ps[8];
#pragma unroll
  for (int i = 0; i < 8; i++) {
    float s = 0.f;
#pragma unroll
    for (int jj = 0; jj < 8; jj++) {
      if (j0 + tc * 8 + jj < N) s += exp2f(acc[i][jj] * SCALE2);
    }
    ps[i] = s;
  }
  __syncthreads();  // done reading Gs/Es
  float* red = smem;  // [128][17]
#pragma unroll
  for (int i = 0; i < 8; i++) red[(tr * 8 + i) * 17 + tc] = ps[i];
  __syncthreads();
  if (tid < 128) {
    float s = 0.f;
#pragma unroll
    for (int k = 0; k < 16; k++) s += red[tid * 17 + k];
    atomicAdd(&s_out[g0 + tid], s);
  }
}

// ---------------- small losses ----------------

__global__ void small_losses_kernel(const int* __restrict__ uids, const int* __restrict__ pos,
                                    const int* __restrict__ neg, const float* __restrict__ Gb,
                                    const float* __restrict__ Eu, const float* __restrict__ Ei,
                                    float* __restrict__ acc) {
  int wid = (blockIdx.x * 256 + threadIdx.x) >> 6;
  int lane = threadIdx.x & 63;
  if (wid >= 2048) return;
  if (wid < 512) {
    int u = uids[wid];
    float p = Gb[(size_t)wid * DD + lane] * Eu[(size_t)u * DD + lane];
    p = wave_red_sum(p);
    if (lane == 0) atomicAdd(&acc[0], fminf(fmaxf(p * (1.0f / TEMP), -5.0f), 5.0f));
  } else if (wid < 1536) {
    int r = wid - 512;
    int i = (r < 512) ? pos[r] : neg[r - 512];
    float p = Gb[(size_t)wid * DD + lane] * Ei[(size_t)i * DD + lane];
    p = wave_red_sum(p);
    if (lane == 0) atomicAdd(&acc[1], fminf(fmaxf(p * (1.0f / TEMP), -5.0f), 5.0f));
  } else {
    int b = wid - 1536;
    int u = uids[b], ip = pos[b], in2 = neg[b];
    float eu = Eu[(size_t)u * DD + lane];
    float sp = wave_red_sum(eu * Ei[(size_t)ip * DD + lane]);
    float sn = wave_red_sum(eu * Ei[(size_t)in2 * DD + lane]);
    if (lane == 0) {
      float x = sp - sn;
      float ls = fminf(x, 0.0f) - log1pf(expf(-fabsf(x)));
      atomicAdd(&acc[2], ls);
    }
  }
}

__global__ void sq_kernel(const float* __restrict__ p0, const float* __restrict__ p1,
                          const float* __restrict__ p2, const float* __restrict__ p3,
                          const float* __restrict__ p4, const float* __restrict__ p5,
                          float* __restrict__ acc) {
  const int n0 = N_U * DD, n1 = N_I * DD, n2 = IN_DIM * DD, n3 = DD, n4 = IN_DIM * DD, n5 = DD;
  const int total = n0 + n1 + n2 + n3 + n4 + n5;
  float s = 0.f;
  for (int i = blockIdx.x * blockDim.x + threadIdx.x; i < total; i += gridDim.x * blockDim.x) {
    int k = i; float v;
    if (k < n0) v = p0[k];
    else { k -= n0; if (k < n1) v = p1[k];
      else { k -= n1; if (k < n2) v = p2[k];
        else { k -= n2; if (k < n3) v = p3[k];
          else { k -= n3; if (k < n4) v = p4[k];
            else { k -= n4; v = p5[k]; } } } } }
    s += v * v;
  }
  s = wave_red_sum(s);
  __shared__ float sw[4];
  int lane = threadIdx.x & 63, w = threadIdx.x >> 6;
  if (lane == 0) sw[w] = s;
  __syncthreads();
  if (threadIdx.x == 0) atomicAdd(acc, sw[0] + sw[1] + sw[2] + sw[3]);
}

__global__ void extra_kernel(const int* __restrict__ unpop, const int* __restrict__ pop,
                             const float* __restrict__ Ei, float* __restrict__ acc) {
  int blk = blockIdx.x;
  int t = threadIdx.x;
  int q = t >> 5, p = t & 31;
  int ui = unpop[blk * 8 + q];
  int pi = pop[blk * 32 + p];
  float s = 0.f;
#pragma unroll
  for (int d = 0; d < DD; d++) {
    float df = Ei[(size_t)ui * DD + d] - Ei[(size_t)pi * DD + d];
    s += df * df;
  }
  float dist = sqrtf(s);
  dist = wave_red_sum(dist);
  __shared__ float sw[4];
  int lane = t & 63, w = t >> 6;
  if (lane == 0) sw[w] = dist;
  __syncthreads();
  if (t == 0) atomicAdd(acc, (sw[0] + sw[1] + sw[2] + sw[3]) * (1.0f / 32.0f));
}

__global__ void finalize_kernel(const float* __restrict__ s_u, const float* __restrict__ s_i,
                                const float* __restrict__ acc, float* __restrict__ out) {
  int tid = threadIdx.x;  // 1024
  float lu = (tid < 512) ? logf(s_u[tid] + 1e-8f) : 0.f;
  float li = logf(s_i[tid] + 1e-8f);
  lu = wave_red_sum(lu);
  li = wave_red_sum(li);
  __shared__ float sa[16], sb[16];
  int lane = tid & 63, w = tid >> 6;
  if (lane == 0) { sa[w] = lu; sb[w] = li; }
  __syncthreads();
  if (tid == 0) {
    float su = 0.f, si = 0.f;
    for (int k = 0; k < 16; k++) { su += sa[k]; si += sb[k]; }
    float neg_score = su / 512.0f + si / 1024.0f;
    float pos_score = acc[0] / 512.0f + acc[1] / 1024.0f;
    float loss_s = neg_score - pos_score;
    float loss_r = -acc[2] / 512.0f;
    float loss_reg = 1e-7f * acc[3];
    float extra = acc[4];
    float loss = loss_r + 0.2f * loss_s + loss_reg + 0.01f * extra;
    out[0] = loss;
    out[1] = loss_r;
    out[2] = 0.2f * loss_s;
  }
}

__global__ void copy3_kernel(const float* __restrict__ m, const float* __restrict__ pa,
                             const float* __restrict__ na, float* __restrict__ out) {
  int i = blockIdx.x * 256 + threadIdx.x;
  if (i < NB * IN_DIM) {
    out[3 + i] = m[i];
    out[3 + NB * IN_DIM + i] = pa[i];
    out[3 + 2 * NB * IN_DIM + i] = na[i];
  }
}

extern "C" void kernel_launch(void* const* d_in, const int* in_sizes, int n_in,
                              void* d_out, int out_size, void* d_ws, size_t ws_size,
                              hipStream_t stream) {
  const int*   uids     = (const int*)d_in[0];
  const int*   pos      = (const int*)d_in[1];
  const int*   neg      = (const int*)d_in[2];
  const int*   adj_rows = (const int*)d_in[3];
  const int*   adj_cols = (const int*)d_in[4];
  const float* adj_vals = (const float*)d_in[5];
  const float* Eu0      = (const float*)d_in[6];
  const float* Ei0      = (const float*)d_in[7];
  const float* umuls    = (const float*)d_in[8];
  const float* vt       = (const float*)d_in[9];
  const float* vmuls    = (const float*)d_in[10];
  const float* ut       = (const float*)d_in[11];
  const float* W_api    = (const float*)d_in[12];
  const float* b_api    = (const float*)d_in[13];
  const float* W_mash   = (const float*)d_in[14];
  const float* b_mash   = (const float*)d_in[15];
  const float* pos_api  = (const float*)d_in[16];
  const float* neg_api  = (const float*)d_in[17];
  const float* mashup   = (const float*)d_in[18];
  const int*   unpop    = (const int*)d_in[19];
  const int*   popi     = (const int*)d_in[20];

  float* out = (float*)d_out;
  float* ws  = (float*)d_ws;
  int*   wsi = (int*)d_ws;

  float* Z_i1   = ws + WS_ZI1;
  int*   counts = wsi + WS_CNT;
  int*   offs   = wsi + WS_OFFS;
  int*   cursor = wsi + WS_CUR;
  int*   bsum   = wsi + WS_BSUM;
  int2*  pairs  = (int2*)(wsi + WS_PAIRS);
  float* T_i    = ws + WS_TI;
  float* T_u    = ws + WS_TU;
  float* Gb     = ws + WS_GB;
  float* s_u    = ws + WS_SU;
  float* s_i    = ws + WS_SI;
  float* acc    = ws + WS_ACC;

  // out layout: [0..3) scalars, then mashup/pos_api/neg_api, then E_u, E_i
  float* Eu_out = out + 1179651;   // also holds Z_u1 between layer 1 and layer 2
  float* Ei_out = out + 7579651;

  hipMemsetAsync(counts, 0, 150001ull * 4ull, stream);
  hipMemsetAsync(T_i, 0, (size_t)WS_SMALL_LEN * 4ull, stream);

  const int NROWS = N_U + N_I;                  // 150000
  const int SCAN_BLKS = (NROWS + 1023) / 1024;  // 147

  hist_kernel<<<(NNZ_N + 255) / 256, 256, 0, stream>>>(adj_rows, adj_cols, counts);
  scan1_kernel<<<SCAN_BLKS, 256, 0, stream>>>(counts, bsum, NROWS);
  scan2_kernel<<<1, 256, 0, stream>>>(bsum, SCAN_BLKS);
  scan3_kernel<<<SCAN_BLKS, 256, 0, stream>>>(counts, bsum, offs, cursor, NROWS);
  scatter_kernel<<<(NNZ_N + 255) / 256, 256, 0, stream>>>(adj_rows, adj_cols, adj_vals, cursor, pairs);

  // layer 1: Z_u1 = A @ Ei0 (stored in Eu_out), Z_i1 = A^T @ Eu0 (ws)
  spmm_gather<<<25000, 256, 0, stream>>>(offs, pairs, Ei0, nullptr, nullptr, Eu_out, N_U);
  spmm_gather<<<12500, 256, 0, stream>>>(offs + N_U, pairs, Eu0, nullptr, nullptr, Z_i1, N_I);

  calcT_kernel<<<256, 256, 0, stream>>>(vt, Ei0, Z_i1, T_i, N_I);
  calcT_kernel<<<256, 256, 0, stream>>>(ut, Eu0, Eu_out, T_u, N_U);
  calcG_kernel<<<384, 256, 0, stream>>>(uids, pos, neg, Eu0, Ei0, umuls, vmuls, T_i, T_u, Gb);

  // layer 2 (i first: reads Z_u1 from Eu_out before it is overwritten)
  spmm_gather<<<12500, 256, 0, stream>>>(offs + N_U, pairs, Eu_out, Ei0, Z_i1, Ei_out, N_I);
  spmm_gather<<<25000, 256, 0, stream>>>(offs, pairs, Z_i1, Eu0, Eu_out, Eu_out, N_U);

  // contrastive exp-sums
  logits_kernel<<<dim3((N_U + 127) / 128, 4), 256, 0, stream>>>(Gb, Eu_out, N_U, s_u);
  logits_kernel<<<dim3((N_I + 127) / 128, 8), 256, 0, stream>>>(Gb + 512 * DD, Ei_out, N_I, s_i);

  small_losses_kernel<<<512, 256, 0, stream>>>(uids, pos, neg, Gb, Eu_out, Ei_out, acc);
  sq_kernel<<<1024, 256, 0, stream>>>(Eu0, Ei0, W_api, b_api, W_mash, b_mash, acc + 3);
  extra_kernel<<<64, 256, 0, stream>>>(unpop, popi, Ei_out, acc + 4);
  finalize_kernel<<<1, 1024, 0, stream>>>(s_u, s_i, acc, out);
  copy3_kernel<<<1536, 256, 0, stream>>>(mashup, pos_api, neg_api, out);
  (void)in_sizes; (void)n_in; (void)out_size; (void)ws_size;
}

// Round 4
// 1080.317 us; speedup vs baseline: 4.5867x; 1.0738x over previous
//
#include <hip/hip_runtime.h>
#include <math.h>

#define N_U 100000
#define N_I 50000
#define DD 64
#define NQ 5
#define NNZ_N 1000000
#define NB 512
#define IN_DIM 768
#define TEMP 0.2f
// (1/TEMP) * log2(e)
#define SCALE2 7.2134752044448169f

// ws dword offsets
#define WS_ZI1   0          // 3,200,000 f  (Z_i1)
#define WS_CNT   3200000    // 150,001 int
#define WS_OFFS  3350016    // 150,001 int
#define WS_CUR   3500032    // 150,000 int
#define WS_BSUM  3650048    // 256 int
#define WS_PAIRS 3650304    // 4,000,000 dwords (2M int2)
#define WS_TI    7650304    // 320 f
#define WS_TU    7650624    // 320 f
#define WS_GB    7650944    // 98,304 f
#define WS_SU    7749248    // 512 f
#define WS_SI    7749760    // 1024 f
#define WS_ACC   7750784    // 8 f
#define WS_SMALL_LEN (7750792 - WS_TI)

__device__ __forceinline__ float wave_red_sum(float v) {
#pragma unroll
  for (int m = 32; m >= 1; m >>= 1) v += __shfl_xor(v, m, 64);
  return v;
}

// ---------------- CSR/CSC build ----------------

__global__ void hist_kernel(const int* __restrict__ rows, const int* __restrict__ cols,
                            int* __restrict__ counts) {
  int e = blockIdx.x * 256 + threadIdx.x;
  if (e >= NNZ_N) return;
  atomicAdd(&counts[rows[e]], 1);
  atomicAdd(&counts[N_U + cols[e]], 1);
}

__global__ void scan1_kernel(const int* __restrict__ counts, int* __restrict__ bsum, int n) {
  int t = threadIdx.x;
  int base = blockIdx.x * 1024 + t * 4;
  int s = 0;
#pragma unroll
  for (int k = 0; k < 4; k++) { int i = base + k; if (i < n) s += counts[i]; }
#pragma unroll
  for (int m = 32; m >= 1; m >>= 1) s += __shfl_xor(s, m, 64);
  __shared__ int sw[4];
  if ((t & 63) == 0) sw[t >> 6] = s;
  __syncthreads();
  if (t == 0) bsum[blockIdx.x] = sw[0] + sw[1] + sw[2] + sw[3];
}

__global__ void scan2_kernel(int* __restrict__ bsum, int nb) {
  int t = threadIdx.x;
  int lane = t & 63, w = t >> 6;
  int orig = (t < nb) ? bsum[t] : 0;
  int v = orig;
#pragma unroll
  for (int m = 1; m < 64; m <<= 1) { int o = __shfl_up(v, m, 64); if (lane >= m) v += o; }
  __shared__ int wt[4];
  if (lane == 63) wt[w] = v;
  __syncthreads();
  int add = 0;
  for (int k = 0; k < w; k++) add += wt[k];
  if (t < nb) bsum[t] = v - orig + add;
}

__global__ void scan3_kernel(const int* __restrict__ counts, const int* __restrict__ bsum,
                             int* __restrict__ offs, int* __restrict__ cursor, int n) {
  int t = threadIdx.x;
  int lane = t & 63, w = t >> 6;
  int base = blockIdx.x * 1024 + t * 4;
  int c[4];
  int s = 0;
#pragma unroll
  for (int k = 0; k < 4; k++) { int i = base + k; c[k] = (i < n) ? counts[i] : 0; s += c[k]; }
  int v = s;
#pragma unroll
  for (int m = 1; m < 64; m <<= 1) { int o = __shfl_up(v, m, 64); if (lane >= m) v += o; }
  __shared__ int wt[4];
  if (lane == 63) wt[w] = v;
  __syncthreads();
  int add = bsum[blockIdx.x];
  for (int k = 0; k < w; k++) add += wt[k];
  int excl = add + v - s;
#pragma unroll
  for (int k = 0; k < 4; k++) {
    int i = base + k;
    if (i < n) {
      offs[i] = excl;
      cursor[i] = excl;
      if (i == n - 1) offs[n] = excl + c[k];
      excl += c[k];
    }
  }
}

// Bucketed scatter: 8 buckets over the combined destination slot space.
// u-rows split 4 x 25000, i-rows split 4 x 12500 (~2 MB of slots each, fits one
// XCD L2). blockIdx.x & 7 selects the bucket; with the %8 XCD round-robin all
// blocks of a bucket share one XCD, so partial lines accumulate before eviction.
#define SC_K 128
__global__ void scatter_bucketed(const int* __restrict__ rows, const int* __restrict__ cols,
                                 const float* __restrict__ vals, int* __restrict__ cursor,
                                 int2* __restrict__ pairs) {
  int b = blockIdx.x & 7;
  int slice = blockIdx.x >> 3;
  const int stride = SC_K * 256;
  bool uside = (b < 4);
  int lo = uside ? b * 25000 : (b - 4) * 12500;
  int hi = uside ? lo + 25000 : lo + 12500;
  for (int e = slice * 256 + threadIdx.x; e < NNZ_N; e += stride) {
    int r = __builtin_nontemporal_load(rows + e);
    int c = __builtin_nontemporal_load(cols + e);
    if (uside) {
      if (r >= lo && r < hi) {
        float v = __builtin_nontemporal_load(vals + e);
        int s1 = atomicAdd(&cursor[r], 1);
        pairs[s1] = make_int2(c, __float_as_int(v));
      }
    } else {
      if (c >= lo && c < hi) {
        float v = __builtin_nontemporal_load(vals + e);
        int s2 = atomicAdd(&cursor[N_U + c], 1);
        pairs[s2] = make_int2(r, __float_as_int(v));
      }
    }
  }
}

// dst[row] = (base0?base0[row]:0) + (base1?base1[row]:0) + sum_k val_k * src[idx_k]
__global__ void spmm_gather(const int* __restrict__ offs, const int2* __restrict__ pairs,
                            const float* __restrict__ src, const float* __restrict__ base0,
                            const float* __restrict__ base1, float* __restrict__ dst,
                            int n_rows) {
  int gid = blockIdx.x * 256 + threadIdx.x;
  int row = gid >> 6, lane = gid & 63;
  if (row >= n_rows) return;
  int s = offs[row], e = offs[row + 1];
  float acc = 0.f;
  for (int k = s; k < e; k++) {
    int2 p = pairs[k];
    acc += __int_as_float(p.y) * src[(size_t)p.x * DD + lane];
  }
  if (base0) acc += base0[(size_t)row * DD + lane];
  if (base1) acc += base1[(size_t)row * DD + lane];
  dst[(size_t)row * DD + lane] = acc;
}

// ---------------- SVD low-rank path ----------------

__global__ void calcT_kernel(const float* __restrict__ vt, const float* __restrict__ A,
                             const float* __restrict__ B, float* __restrict__ T, int N) {
  int lane = threadIdx.x & 63;
  int wave = (blockIdx.x * blockDim.x + threadIdx.x) >> 6;
  int nw = (gridDim.x * blockDim.x) >> 6;
  float a0 = 0.f, a1 = 0.f, a2 = 0.f, a3 = 0.f, a4 = 0.f;
  for (int j = wave; j < N; j += nw) {
    float x = A[(size_t)j * DD + lane] + B[(size_t)j * DD + lane];
    a0 += vt[0 * N + j] * x;
    a1 += vt[1 * N + j] * x;
    a2 += vt[2 * N + j] * x;
    a3 += vt[3 * N + j] * x;
    a4 += vt[4 * N + j] * x;
  }
  atomicAdd(&T[0 * DD + lane], a0);
  atomicAdd(&T[1 * DD + lane], a1);
  atomicAdd(&T[2 * DD + lane], a2);
  atomicAdd(&T[3 * DD + lane], a3);
  atomicAdd(&T[4 * DD + lane], a4);
}

__global__ void calcG_kernel(const int* __restrict__ uids, const int* __restrict__ pos,
                             const int* __restrict__ neg,
                             const float* __restrict__ Eu0, const float* __restrict__ Ei0,
                             const float* __restrict__ umuls, const float* __restrict__ vmuls,
                             const float* __restrict__ Ti, const float* __restrict__ Tu,
                             float* __restrict__ Gb) {
  int gid = blockIdx.x * 256 + threadIdx.x;
  if (gid >= 1536 * DD) return;
  int rrow = gid >> 6, d = gid & 63;
  float g;
  if (rrow < 512) {
    int u = uids[rrow];
    g = Eu0[(size_t)u * DD + d];
#pragma unroll
    for (int q = 0; q < NQ; q++) g += umuls[u * NQ + q] * Ti[q * DD + d];
  } else {
    int rr = rrow - 512;
    int i = (rr < 512) ? pos[rr] : neg[rr - 512];
    g = Ei0[(size_t)i * DD + d];
#pragma unroll
    for (int q = 0; q < NQ; q++) g += vmuls[i * NQ + q] * Tu[q * DD + d];
  }
  Gb[gid] = g;
}

// ---------------- contrastive exp-sums (register-blocked GEMM style) ----------------
__global__ __launch_bounds__(256) void logits_kernel(
    const float* __restrict__ Gb, const float* __restrict__ E,
    int N, float* __restrict__ s_out) {
  __shared__ float smem[4096];  // Gs [16][128] | Es [16][128]; reused as red[128][17]
  float* Gs = smem;
  float* Es = smem + 2048;

  int tid = threadIdx.x;
  int tr = tid >> 4;
  int tc = tid & 15;
  int g0 = blockIdx.y * 128;
  int j0 = blockIdx.x * 128;

  float acc[8][8];
#pragma unroll
  for (int i = 0; i < 8; i++)
#pragma unroll
    for (int j = 0; j < 8; j++) acc[i][j] = 0.f;

  int sr = tid >> 1;
  int dh = tid & 1;

  for (int dc = 0; dc < 4; dc++) {
    if (dc) __syncthreads();
    {
      const float* p = Gb + (size_t)(g0 + sr) * DD + dc * 16 + dh * 8;
      float4 x = *(const float4*)p;
      float4 y = *(const float4*)(p + 4);
      int db = dh * 8;
      Gs[(db + 0) * 128 + sr] = x.x; Gs[(db + 1) * 128 + sr] = x.y;
      Gs[(db + 2) * 128 + sr] = x.z; Gs[(db + 3) * 128 + sr] = x.w;
      Gs[(db + 4) * 128 + sr] = y.x; Gs[(db + 5) * 128 + sr] = y.y;
      Gs[(db + 6) * 128 + sr] = y.z; Gs[(db + 7) * 128 + sr] = y.w;
    }
    {
      float4 x = make_float4(0.f, 0.f, 0.f, 0.f), y = x;
      if (j0 + sr < N) {
        const float* q = E + (size_t)(j0 + sr) * DD + dc * 16 + dh * 8;
        x = *(const float4*)q;
        y = *(const float4*)(q + 4);
      }
      int db = dh * 8;
      Es[(db + 0) * 128 + sr] = x.x; Es[(db + 1) * 128 + sr] = x.y;
      Es[(db + 2) * 128 + sr] = x.z; Es[(db + 3) * 128 + sr] = x.w;
      Es[(db + 4) * 128 + sr] = y.x; Es[(db + 5) * 128 + sr] = y.y;
      Es[(db + 6) * 128 + sr] = y.z; Es[(db + 7) * 128 + sr] = y.w;
    }
    __syncthreads();
#pragma unroll
    for (int d = 0; d < 16; d++) {
      float4 a0 = *(const float4*)&Gs[d * 128 + tr * 8];
      float4 a1 = *(const float4*)&Gs[d * 128 + tr * 8 + 4];
      float4 b0 = *(const float4*)&Es[d * 128 + tc * 8];
      float4 b1 = *(const float4*)&Es[d * 128 + tc * 8 + 4];
      float av[8] = {a0.x, a0.y, a0.z, a0.w, a1.x, a1.y, a1.z, a1.w};
      float bv[8] = {b0.x, b0.y, b0.z, b0.w, b1.x, b1.y, b1.z, b1.w};
#pragma unroll
      for (int i = 0; i < 8; i++)
#pragma unroll
        for (int j = 0; j < 8; j++) acc[i][j] += av[i] * bv[j];
    }
  }

  float ps[8];
#pragma unroll
  for (int i = 0; i < 8; i++) {
    float s = 0.f;
#pragma unroll
    for (int jj = 0; jj < 8; jj++) {
      if (j0 + tc * 8 + jj < N) s += exp2f(acc[i][jj] * SCALE2);
    }
    ps[i] = s;
  }
  __syncthreads();
  float* red = smem;
#pragma unroll
  for (int i = 0; i < 8; i++) red[(tr * 8 + i) * 17 + tc] = ps[i];
  __syncthreads();
  if (tid < 128) {
    float s = 0.f;
#pragma unroll
    for (int k = 0; k < 16; k++) s += red[tid * 17 + k];
    atomicAdd(&s_out[g0 + tid], s);
  }
}

// ---------------- small losses ----------------

__global__ void small_losses_kernel(const int* __restrict__ uids, const int* __restrict__ pos,
                                    const int* __restrict__ neg, const float* __restrict__ Gb,
                                    const float* __restrict__ Eu, const float* __restrict__ Ei,
                                    float* __restrict__ acc) {
  int wid = (blockIdx.x * 256 + threadIdx.x) >> 6;
  int lane = threadIdx.x & 63;
  if (wid >= 2048) return;
  if (wid < 512) {
    int u = uids[wid];
    float p = Gb[(size_t)wid * DD + lane] * Eu[(size_t)u * DD + lane];
    p = wave_red_sum(p);
    if (lane == 0) atomicAdd(&acc[0], fminf(fmaxf(p * (1.0f / TEMP), -5.0f), 5.0f));
  } else if (wid < 1536) {
    int r = wid - 512;
    int i = (r < 512) ? pos[r] : neg[r - 512];
    float p = Gb[(size_t)wid * DD + lane] * Ei[(size_t)i * DD + lane];
    p = wave_red_sum(p);
    if (lane == 0) atomicAdd(&acc[1], fminf(fmaxf(p * (1.0f / TEMP), -5.0f), 5.0f));
  } else {
    int b = wid - 1536;
    int u = uids[b], ip = pos[b], in2 = neg[b];
    float eu = Eu[(size_t)u * DD + lane];
    float sp = wave_red_sum(eu * Ei[(size_t)ip * DD + lane]);
    float sn = wave_red_sum(eu * Ei[(size_t)in2 * DD + lane]);
    if (lane == 0) {
      float x = sp - sn;
      float ls = fminf(x, 0.0f) - log1pf(expf(-fabsf(x)));
      atomicAdd(&acc[2], ls);
    }
  }
}

__global__ void sq_kernel(const float* __restrict__ p0, const float* __restrict__ p1,
                          const float* __restrict__ p2, const float* __restrict__ p3,
                          const float* __restrict__ p4, const float* __restrict__ p5,
                          float* __restrict__ acc) {
  const int n0 = N_U * DD, n1 = N_I * DD, n2 = IN_DIM * DD, n3 = DD, n4 = IN_DIM * DD, n5 = DD;
  const int total = n0 + n1 + n2 + n3 + n4 + n5;
  float s = 0.f;
  for (int i = blockIdx.x * blockDim.x + threadIdx.x; i < total; i += gridDim.x * blockDim.x) {
    int k = i; float v;
    if (k < n0) v = p0[k];
    else { k -= n0; if (k < n1) v = p1[k];
      else { k -= n1; if (k < n2) v = p2[k];
        else { k -= n2; if (k < n3) v = p3[k];
          else { k -= n3; if (k < n4) v = p4[k];
            else { k -= n4; v = p5[k]; } } } } }
    s += v * v;
  }
  s = wave_red_sum(s);
  __shared__ float sw[4];
  int lane = threadIdx.x & 63, w = threadIdx.x >> 6;
  if (lane == 0) sw[w] = s;
  __syncthreads();
  if (threadIdx.x == 0) atomicAdd(acc, sw[0] + sw[1] + sw[2] + sw[3]);
}

__global__ void extra_kernel(const int* __restrict__ unpop, const int* __restrict__ pop,
                             const float* __restrict__ Ei, float* __restrict__ acc) {
  int blk = blockIdx.x;
  int t = threadIdx.x;
  int q = t >> 5, p = t & 31;
  int ui = unpop[blk * 8 + q];
  int pi = pop[blk * 32 + p];
  float s = 0.f;
#pragma unroll
  for (int d = 0; d < DD; d++) {
    float df = Ei[(size_t)ui * DD + d] - Ei[(size_t)pi * DD + d];
    s += df * df;
  }
  float dist = sqrtf(s);
  dist = wave_red_sum(dist);
  __shared__ float sw[4];
  int lane = t & 63, w = t >> 6;
  if (lane == 0) sw[w] = dist;
  __syncthreads();
  if (t == 0) atomicAdd(acc, (sw[0] + sw[1] + sw[2] + sw[3]) * (1.0f / 32.0f));
}

__global__ void finalize_kernel(const float* __restrict__ s_u, const float* __restrict__ s_i,
                                const float* __restrict__ acc, float* __restrict__ out) {
  int tid = threadIdx.x;  // 1024
  float lu = (tid < 512) ? logf(s_u[tid] + 1e-8f) : 0.f;
  float li = logf(s_i[tid] + 1e-8f);
  lu = wave_red_sum(lu);
  li = wave_red_sum(li);
  __shared__ float sa[16], sb[16];
  int lane = tid & 63, w = tid >> 6;
  if (lane == 0) { sa[w] = lu; sb[w] = li; }
  __syncthreads();
  if (tid == 0) {
    float su = 0.f, si = 0.f;
    for (int k = 0; k < 16; k++) { su += sa[k]; si += sb[k]; }
    float neg_score = su / 512.0f + si / 1024.0f;
    float pos_score = acc[0] / 512.0f + acc[1] / 1024.0f;
    float loss_s = neg_score - pos_score;
    float loss_r = -acc[2] / 512.0f;
    float loss_reg = 1e-7f * acc[3];
    float extra = acc[4];
    float loss = loss_r + 0.2f * loss_s + loss_reg + 0.01f * extra;
    out[0] = loss;
    out[1] = loss_r;
    out[2] = 0.2f * loss_s;
  }
}

__global__ void copy3_kernel(const float* __restrict__ m, const float* __restrict__ pa,
                             const float* __restrict__ na, float* __restrict__ out) {
  int i = blockIdx.x * 256 + threadIdx.x;
  if (i < NB * IN_DIM) {
    out[3 + i] = m[i];
    out[3 + NB * IN_DIM + i] = pa[i];
    out[3 + 2 * NB * IN_DIM + i] = na[i];
  }
}

extern "C" void kernel_launch(void* const* d_in, const int* in_sizes, int n_in,
                              void* d_out, int out_size, void* d_ws, size_t ws_size,
                              hipStream_t stream) {
  const int*   uids     = (const int*)d_in[0];
  const int*   pos      = (const int*)d_in[1];
  const int*   neg      = (const int*)d_in[2];
  const int*   adj_rows = (const int*)d_in[3];
  const int*   adj_cols = (const int*)d_in[4];
  const float* adj_vals = (const float*)d_in[5];
  const float* Eu0      = (const float*)d_in[6];
  const float* Ei0      = (const float*)d_in[7];
  const float* umuls    = (const float*)d_in[8];
  const float* vt       = (const float*)d_in[9];
  const float* vmuls    = (const float*)d_in[10];
  const float* ut       = (const float*)d_in[11];
  const float* W_api    = (const float*)d_in[12];
  const float* b_api    = (const float*)d_in[13];
  const float* W_mash   = (const float*)d_in[14];
  const float* b_mash   = (const float*)d_in[15];
  const float* pos_api  = (const float*)d_in[16];
  const float* neg_api  = (const float*)d_in[17];
  const float* mashup   = (const float*)d_in[18];
  const int*   unpop    = (const int*)d_in[19];
  const int*   popi     = (const int*)d_in[20];

  float* out = (float*)d_out;
  float* ws  = (float*)d_ws;
  int*   wsi = (int*)d_ws;

  float* Z_i1   = ws + WS_ZI1;
  int*   counts = wsi + WS_CNT;
  int*   offs   = wsi + WS_OFFS;
  int*   cursor = wsi + WS_CUR;
  int*   bsum   = wsi + WS_BSUM;
  int2*  pairs  = (int2*)(wsi + WS_PAIRS);
  float* T_i    = ws + WS_TI;
  float* T_u    = ws + WS_TU;
  float* Gb     = ws + WS_GB;
  float* s_u    = ws + WS_SU;
  float* s_i    = ws + WS_SI;
  float* acc    = ws + WS_ACC;

  // out layout: [0..3) scalars, then mashup/pos_api/neg_api, then E_u, E_i
  float* Eu_out = out + 1179651;   // also holds Z_u1 between layer 1 and layer 2
  float* Ei_out = out + 7579651;

  hipMemsetAsync(counts, 0, 150001ull * 4ull, stream);
  hipMemsetAsync(T_i, 0, (size_t)WS_SMALL_LEN * 4ull, stream);

  const int NROWS = N_U + N_I;                  // 150000
  const int SCAN_BLKS = (NROWS + 1023) / 1024;  // 147

  hist_kernel<<<(NNZ_N + 255) / 256, 256, 0, stream>>>(adj_rows, adj_cols, counts);
  scan1_kernel<<<SCAN_BLKS, 256, 0, stream>>>(counts, bsum, NROWS);
  scan2_kernel<<<1, 256, 0, stream>>>(bsum, SCAN_BLKS);
  scan3_kernel<<<SCAN_BLKS, 256, 0, stream>>>(counts, bsum, offs, cursor, NROWS);
  scatter_bucketed<<<8 * SC_K, 256, 0, stream>>>(adj_rows, adj_cols, adj_vals, cursor, pairs);

  // layer 1: Z_u1 = A @ Ei0 (stored in Eu_out), Z_i1 = A^T @ Eu0 (ws)
  spmm_gather<<<25000, 256, 0, stream>>>(offs, pairs, Ei0, nullptr, nullptr, Eu_out, N_U);
  spmm_gather<<<12500, 256, 0, stream>>>(offs + N_U, pairs, Eu0, nullptr, nullptr, Z_i1, N_I);

  calcT_kernel<<<256, 256, 0, stream>>>(vt, Ei0, Z_i1, T_i, N_I);
  calcT_kernel<<<256, 256, 0, stream>>>(ut, Eu0, Eu_out, T_u, N_U);
  calcG_kernel<<<384, 256, 0, stream>>>(uids, pos, neg, Eu0, Ei0, umuls, vmuls, T_i, T_u, Gb);

  // layer 2 (i first: reads Z_u1 from Eu_out before it is overwritten)
  spmm_gather<<<12500, 256, 0, stream>>>(offs + N_U, pairs, Eu_out, Ei0, Z_i1, Ei_out, N_I);
  spmm_gather<<<25000, 256, 0, stream>>>(offs, pairs, Z_i1, Eu0, Eu_out, Eu_out, N_U);

  // contrastive exp-sums
  logits_kernel<<<dim3((N_U + 127) / 128, 4), 256, 0, stream>>>(Gb, Eu_out, N_U, s_u);
  logits_kernel<<<dim3((N_I + 127) / 128, 8), 256, 0, stream>>>(Gb + 512 * DD, Ei_out, N_I, s_i);

  small_losses_kernel<<<512, 256, 0, stream>>>(uids, pos, neg, Gb, Eu_out, Ei_out, acc);
  sq_kernel<<<1024, 256, 0, stream>>>(Eu0, Ei0, W_api, b_api, W_mash, b_mash, acc + 3);
  extra_kernel<<<64, 256, 0, stream>>>(unpop, popi, Ei_out, acc + 4);
  finalize_kernel<<<1, 1024, 0, stream>>>(s_u, s_i, acc, out);
  copy3_kernel<<<1536, 256, 0, stream>>>(mashup, pos_api, neg_api, out);
  (void)in_sizes; (void)n_in; (void)out_size; (void)ws_size;
}

// Round 5
// 815.209 us; speedup vs baseline: 6.0783x; 1.3252x over previous
//
#include <hip/hip_runtime.h>
#include <math.h>

#define N_U 100000
#define N_I 50000
#define DD 64
#define NQ 5
#define NNZ_N 1000000
#define NB 512
#define IN_DIM 768
#define TEMP 0.2f
// (1/TEMP) * log2(e)
#define SCALE2 7.2134752044448169f

// ws dword offsets
#define WS_ZI1   0          // 3,200,000 f  (Z_i1; later reused as EuB16)
#define WS_CNT   3200000    // 150,001 int
#define WS_OFFS  3350016    // 150,001 int
#define WS_CUR   3500032    // 150,000 int
#define WS_BSUM  3650048    // 256 int
#define WS_PAIRS 3650304    // 4,000,000 dwords (2M int2; later reused as EiB16)
#define WS_TI    7650304    // 320 f
#define WS_TU    7650624    // 320 f
#define WS_GB    7650944    // 98,304 f
#define WS_SU    7749248    // 512 f
#define WS_SI    7749760    // 1024 f
#define WS_ACC   7750784    // 8 f
#define WS_SMALL_LEN (7750792 - WS_TI)
#define WS_GB16  7750792    // 49,152 dwords (1536*64 bf16)

typedef short short8 __attribute__((ext_vector_type(8)));
typedef float float4v __attribute__((ext_vector_type(4)));

__device__ __forceinline__ float wave_red_sum(float v) {
#pragma unroll
  for (int m = 32; m >= 1; m >>= 1) v += __shfl_xor(v, m, 64);
  return v;
}

__device__ __forceinline__ unsigned short f2bf(float f) {
  unsigned u = __float_as_uint(f);
  unsigned r = (u + 0x7fffu + ((u >> 16) & 1u)) >> 16;
  return (unsigned short)r;
}

// ---------------- CSR/CSC build ----------------

__global__ void hist_kernel(const int* __restrict__ rows, const int* __restrict__ cols,
                            int* __restrict__ counts) {
  int e = blockIdx.x * 256 + threadIdx.x;
  if (e >= NNZ_N) return;
  atomicAdd(&counts[rows[e]], 1);
  atomicAdd(&counts[N_U + cols[e]], 1);
}

__global__ void scan1_kernel(const int* __restrict__ counts, int* __restrict__ bsum, int n) {
  int t = threadIdx.x;
  int base = blockIdx.x * 1024 + t * 4;
  int s = 0;
#pragma unroll
  for (int k = 0; k < 4; k++) { int i = base + k; if (i < n) s += counts[i]; }
#pragma unroll
  for (int m = 32; m >= 1; m >>= 1) s += __shfl_xor(s, m, 64);
  __shared__ int sw[4];
  if ((t & 63) == 0) sw[t >> 6] = s;
  __syncthreads();
  if (t == 0) bsum[blockIdx.x] = sw[0] + sw[1] + sw[2] + sw[3];
}

__global__ void scan2_kernel(int* __restrict__ bsum, int nb) {
  int t = threadIdx.x;
  int lane = t & 63, w = t >> 6;
  int orig = (t < nb) ? bsum[t] : 0;
  int v = orig;
#pragma unroll
  for (int m = 1; m < 64; m <<= 1) { int o = __shfl_up(v, m, 64); if (lane >= m) v += o; }
  __shared__ int wt[4];
  if (lane == 63) wt[w] = v;
  __syncthreads();
  int add = 0;
  for (int k = 0; k < w; k++) add += wt[k];
  if (t < nb) bsum[t] = v - orig + add;
}

__global__ void scan3_kernel(const int* __restrict__ counts, const int* __restrict__ bsum,
                             int* __restrict__ offs, int* __restrict__ cursor, int n) {
  int t = threadIdx.x;
  int lane = t & 63, w = t >> 6;
  int base = blockIdx.x * 1024 + t * 4;
  int c[4];
  int s = 0;
#pragma unroll
  for (int k = 0; k < 4; k++) { int i = base + k; c[k] = (i < n) ? counts[i] : 0; s += c[k]; }
  int v = s;
#pragma unroll
  for (int m = 1; m < 64; m <<= 1) { int o = __shfl_up(v, m, 64); if (lane >= m) v += o; }
  __shared__ int wt[4];
  if (lane == 63) wt[w] = v;
  __syncthreads();
  int add = bsum[blockIdx.x];
  for (int k = 0; k < w; k++) add += wt[k];
  int excl = add + v - s;
#pragma unroll
  for (int k = 0; k < 4; k++) {
    int i = base + k;
    if (i < n) {
      offs[i] = excl;
      cursor[i] = excl;
      if (i == n - 1) offs[n] = excl + c[k];
      excl += c[k];
    }
  }
}

// Bucketed scatter (XCD L2 write locality; see round-4 notes).
#define SC_K 128
__global__ void scatter_bucketed(const int* __restrict__ rows, const int* __restrict__ cols,
                                 const float* __restrict__ vals, int* __restrict__ cursor,
                                 int2* __restrict__ pairs) {
  int b = blockIdx.x & 7;
  int slice = blockIdx.x >> 3;
  const int stride = SC_K * 256;
  bool uside = (b < 4);
  int lo = uside ? b * 25000 : (b - 4) * 12500;
  int hi = uside ? lo + 25000 : lo + 12500;
  for (int e = slice * 256 + threadIdx.x; e < NNZ_N; e += stride) {
    int r = __builtin_nontemporal_load(rows + e);
    int c = __builtin_nontemporal_load(cols + e);
    if (uside) {
      if (r >= lo && r < hi) {
        float v = __builtin_nontemporal_load(vals + e);
        int s1 = atomicAdd(&cursor[r], 1);
        pairs[s1] = make_int2(c, __float_as_int(v));
      }
    } else {
      if (c >= lo && c < hi) {
        float v = __builtin_nontemporal_load(vals + e);
        int s2 = atomicAdd(&cursor[N_U + c], 1);
        pairs[s2] = make_int2(r, __float_as_int(v));
      }
    }
  }
}

// dst[row] = (base0?base0[row]:0) + (base1?base1[row]:0) + sum_k val_k * src[idx_k]
// 4x unrolled pair loop to break the pairs->gather dependent-load chain.
__global__ void spmm_gather(const int* __restrict__ offs, const int2* __restrict__ pairs,
                            const float* __restrict__ src, const float* __restrict__ base0,
                            const float* __restrict__ base1, float* __restrict__ dst,
                            int n_rows) {
  int gid = blockIdx.x * 256 + threadIdx.x;
  int row = gid >> 6, lane = gid & 63;
  if (row >= n_rows) return;
  int s = offs[row], e = offs[row + 1];
  float acc = 0.f;
  int k = s;
  for (; k + 4 <= e; k += 4) {
    int2 p0 = pairs[k + 0];
    int2 p1 = pairs[k + 1];
    int2 p2 = pairs[k + 2];
    int2 p3 = pairs[k + 3];
    float x0 = src[(size_t)p0.x * DD + lane];
    float x1 = src[(size_t)p1.x * DD + lane];
    float x2 = src[(size_t)p2.x * DD + lane];
    float x3 = src[(size_t)p3.x * DD + lane];
    acc += __int_as_float(p0.y) * x0;
    acc += __int_as_float(p1.y) * x1;
    acc += __int_as_float(p2.y) * x2;
    acc += __int_as_float(p3.y) * x3;
  }
  for (; k < e; k++) {
    int2 p = pairs[k];
    acc += __int_as_float(p.y) * src[(size_t)p.x * DD + lane];
  }
  if (base0) acc += base0[(size_t)row * DD + lane];
  if (base1) acc += base1[(size_t)row * DD + lane];
  dst[(size_t)row * DD + lane] = acc;
}

// ---------------- SVD low-rank path ----------------

__global__ void calcT_kernel(const float* __restrict__ vt, const float* __restrict__ A,
                             const float* __restrict__ B, float* __restrict__ T, int N) {
  int lane = threadIdx.x & 63;
  int wave = (blockIdx.x * blockDim.x + threadIdx.x) >> 6;
  int nw = (gridDim.x * blockDim.x) >> 6;
  float a0 = 0.f, a1 = 0.f, a2 = 0.f, a3 = 0.f, a4 = 0.f;
  for (int j = wave; j < N; j += nw) {
    float x = A[(size_t)j * DD + lane] + B[(size_t)j * DD + lane];
    a0 += vt[0 * N + j] * x;
    a1 += vt[1 * N + j] * x;
    a2 += vt[2 * N + j] * x;
    a3 += vt[3 * N + j] * x;
    a4 += vt[4 * N + j] * x;
  }
  atomicAdd(&T[0 * DD + lane], a0);
  atomicAdd(&T[1 * DD + lane], a1);
  atomicAdd(&T[2 * DD + lane], a2);
  atomicAdd(&T[3 * DD + lane], a3);
  atomicAdd(&T[4 * DD + lane], a4);
}

__global__ void calcG_kernel(const int* __restrict__ uids, const int* __restrict__ pos,
                             const int* __restrict__ neg,
                             const float* __restrict__ Eu0, const float* __restrict__ Ei0,
                             const float* __restrict__ umuls, const float* __restrict__ vmuls,
                             const float* __restrict__ Ti, const float* __restrict__ Tu,
                             float* __restrict__ Gb) {
  int gid = blockIdx.x * 256 + threadIdx.x;
  if (gid >= 1536 * DD) return;
  int rrow = gid >> 6, d = gid & 63;
  float g;
  if (rrow < 512) {
    int u = uids[rrow];
    g = Eu0[(size_t)u * DD + d];
#pragma unroll
    for (int q = 0; q < NQ; q++) g += umuls[u * NQ + q] * Ti[q * DD + d];
  } else {
    int rr = rrow - 512;
    int i = (rr < 512) ? pos[rr] : neg[rr - 512];
    g = Ei0[(size_t)i * DD + d];
#pragma unroll
    for (int q = 0; q < NQ; q++) g += vmuls[i * NQ + q] * Tu[q * DD + d];
  }
  Gb[gid] = g;
}

// fp32 -> bf16 convert (n multiple of 4)
__global__ void cvt_bf16_kernel(const float* __restrict__ in, unsigned short* __restrict__ outp,
                                int n4) {
  int i = blockIdx.x * 256 + threadIdx.x;
  if (i >= n4) return;
  float4 x = *(const float4*)(in + (size_t)i * 4);
  ushort4 o;
  o.x = f2bf(x.x); o.y = f2bf(x.y); o.z = f2bf(x.z); o.w = f2bf(x.w);
  *(ushort4*)(outp + (size_t)i * 4) = o;
}

// ---------------- contrastive exp-sums via MFMA ----------------
// Block: 128 g-rows (8 groups of 16) x streamed 16-j tiles of E (bf16, global).
// A layout: A[m=lane&15][k=quad*8+j]; C/D: col=lane&15, row=quad*4+reg.
#define GPB 8
__global__ __launch_bounds__(256) void logits_mfma(
    const unsigned short* __restrict__ Gb16, const unsigned short* __restrict__ Eb16,
    int N, float* __restrict__ s_out) {
  int tid = threadIdx.x;
  int lane = tid & 63;
  int wave = tid >> 6;
  int col = lane & 15;
  int quad = lane >> 4;
  int gbase = blockIdx.y * (GPB * 16);

  short8 afrag[GPB][2];
#pragma unroll
  for (int gg = 0; gg < GPB; gg++) {
    const unsigned short* gp = Gb16 + (size_t)(gbase + gg * 16 + col) * 64 + quad * 8;
    afrag[gg][0] = *(const short8*)(gp);
    afrag[gg][1] = *(const short8*)(gp + 32);
  }

  float psum[GPB][4];
#pragma unroll
  for (int gg = 0; gg < GPB; gg++)
#pragma unroll
    for (int r = 0; r < 4; r++) psum[gg][r] = 0.f;

  int nt = N >> 4;  // N divisible by 16 (100000, 50000)
  int wid = blockIdx.x * 4 + wave;
  int nw = gridDim.x * 4;
  for (int t = wid; t < nt; t += nw) {
    const unsigned short* ep = Eb16 + (size_t)(t * 16 + col) * 64 + quad * 8;
    short8 b0 = *(const short8*)(ep);
    short8 b1 = *(const short8*)(ep + 32);
#pragma unroll
    for (int gg = 0; gg < GPB; gg++) {
      float4v acc = {0.f, 0.f, 0.f, 0.f};
      acc = __builtin_amdgcn_mfma_f32_16x16x32_bf16(afrag[gg][0], b0, acc, 0, 0, 0);
      acc = __builtin_amdgcn_mfma_f32_16x16x32_bf16(afrag[gg][1], b1, acc, 0, 0, 0);
#pragma unroll
      for (int r = 0; r < 4; r++) psum[gg][r] += exp2f(acc[r] * SCALE2);
    }
  }
  // reduce across the 16 cols (low 4 lane bits)
#pragma unroll
  for (int gg = 0; gg < GPB; gg++)
#pragma unroll
    for (int r = 0; r < 4; r++) {
      float v = psum[gg][r];
#pragma unroll
      for (int m = 1; m <= 8; m <<= 1) v += __shfl_xor(v, m, 64);
      psum[gg][r] = v;
    }
  if (col == 0) {
#pragma unroll
    for (int gg = 0; gg < GPB; gg++)
#pragma unroll
      for (int r = 0; r < 4; r++)
        atomicAdd(&s_out[gbase + gg * 16 + quad * 4 + r], psum[gg][r]);
  }
}

// ---------------- small losses ----------------

__global__ void small_losses_kernel(const int* __restrict__ uids, const int* __restrict__ pos,
                                    const int* __restrict__ neg, const float* __restrict__ Gb,
                                    const float* __restrict__ Eu, const float* __restrict__ Ei,
                                    float* __restrict__ acc) {
  int wid = (blockIdx.x * 256 + threadIdx.x) >> 6;
  int lane = threadIdx.x & 63;
  if (wid >= 2048) return;
  if (wid < 512) {
    int u = uids[wid];
    float p = Gb[(size_t)wid * DD + lane] * Eu[(size_t)u * DD + lane];
    p = wave_red_sum(p);
    if (lane == 0) atomicAdd(&acc[0], fminf(fmaxf(p * (1.0f / TEMP), -5.0f), 5.0f));
  } else if (wid < 1536) {
    int r = wid - 512;
    int i = (r < 512) ? pos[r] : neg[r - 512];
    float p = Gb[(size_t)wid * DD + lane] * Ei[(size_t)i * DD + lane];
    p = wave_red_sum(p);
    if (lane == 0) atomicAdd(&acc[1], fminf(fmaxf(p * (1.0f / TEMP), -5.0f), 5.0f));
  } else {
    int b = wid - 1536;
    int u = uids[b], ip = pos[b], in2 = neg[b];
    float eu = Eu[(size_t)u * DD + lane];
    float sp = wave_red_sum(eu * Ei[(size_t)ip * DD + lane]);
    float sn = wave_red_sum(eu * Ei[(size_t)in2 * DD + lane]);
    if (lane == 0) {
      float x = sp - sn;
      float ls = fminf(x, 0.0f) - log1pf(expf(-fabsf(x)));
      atomicAdd(&acc[2], ls);
    }
  }
}

__global__ void sq_kernel(const float* __restrict__ p0, const float* __restrict__ p1,
                          const float* __restrict__ p2, const float* __restrict__ p3,
                          const float* __restrict__ p4, const float* __restrict__ p5,
                          float* __restrict__ acc) {
  const int n0 = N_U * DD, n1 = N_I * DD, n2 = IN_DIM * DD, n3 = DD, n4 = IN_DIM * DD, n5 = DD;
  const int total = n0 + n1 + n2 + n3 + n4 + n5;
  float s = 0.f;
  for (int i = blockIdx.x * blockDim.x + threadIdx.x; i < total; i += gridDim.x * blockDim.x) {
    int k = i; float v;
    if (k < n0) v = p0[k];
    else { k -= n0; if (k < n1) v = p1[k];
      else { k -= n1; if (k < n2) v = p2[k];
        else { k -= n2; if (k < n3) v = p3[k];
          else { k -= n3; if (k < n4) v = p4[k];
            else { k -= n4; v = p5[k]; } } } } }
    s += v * v;
  }
  s = wave_red_sum(s);
  __shared__ float sw[4];
  int lane = threadIdx.x & 63, w = threadIdx.x >> 6;
  if (lane == 0) sw[w] = s;
  __syncthreads();
  if (threadIdx.x == 0) atomicAdd(acc, sw[0] + sw[1] + sw[2] + sw[3]);
}

__global__ void extra_kernel(const int* __restrict__ unpop, const int* __restrict__ pop,
                             const float* __restrict__ Ei, float* __restrict__ acc) {
  int blk = blockIdx.x;
  int t = threadIdx.x;
  int q = t >> 5, p = t & 31;
  int ui = unpop[blk * 8 + q];
  int pi = pop[blk * 32 + p];
  float s = 0.f;
#pragma unroll
  for (int d = 0; d < DD; d++) {
    float df = Ei[(size_t)ui * DD + d] - Ei[(size_t)pi * DD + d];
    s += df * df;
  }
  float dist = sqrtf(s);
  dist = wave_red_sum(dist);
  __shared__ float sw[4];
  int lane = t & 63, w = t >> 6;
  if (lane == 0) sw[w] = dist;
  __syncthreads();
  if (t == 0) atomicAdd(acc, (sw[0] + sw[1] + sw[2] + sw[3]) * (1.0f / 32.0f));
}

__global__ void finalize_kernel(const float* __restrict__ s_u, const float* __restrict__ s_i,
                                const float* __restrict__ acc, float* __restrict__ out) {
  int tid = threadIdx.x;  // 1024
  float lu = (tid < 512) ? logf(s_u[tid] + 1e-8f) : 0.f;
  float li = logf(s_i[tid] + 1e-8f);
  lu = wave_red_sum(lu);
  li = wave_red_sum(li);
  __shared__ float sa[16], sb[16];
  int lane = tid & 63, w = tid >> 6;
  if (lane == 0) { sa[w] = lu; sb[w] = li; }
  __syncthreads();
  if (tid == 0) {
    float su = 0.f, si = 0.f;
    for (int k = 0; k < 16; k++) { su += sa[k]; si += sb[k]; }
    float neg_score = su / 512.0f + si / 1024.0f;
    float pos_score = acc[0] / 512.0f + acc[1] / 1024.0f;
    float loss_s = neg_score - pos_score;
    float loss_r = -acc[2] / 512.0f;
    float loss_reg = 1e-7f * acc[3];
    float extra = acc[4];
    float loss = loss_r + 0.2f * loss_s + loss_reg + 0.01f * extra;
    out[0] = loss;
    out[1] = loss_r;
    out[2] = 0.2f * loss_s;
  }
}

__global__ void copy3_kernel(const float* __restrict__ m, const float* __restrict__ pa,
                             const float* __restrict__ na, float* __restrict__ out) {
  int i = blockIdx.x * 256 + threadIdx.x;
  if (i < NB * IN_DIM) {
    out[3 + i] = m[i];
    out[3 + NB * IN_DIM + i] = pa[i];
    out[3 + 2 * NB * IN_DIM + i] = na[i];
  }
}

extern "C" void kernel_launch(void* const* d_in, const int* in_sizes, int n_in,
                              void* d_out, int out_size, void* d_ws, size_t ws_size,
                              hipStream_t stream) {
  const int*   uids     = (const int*)d_in[0];
  const int*   pos      = (const int*)d_in[1];
  const int*   neg      = (const int*)d_in[2];
  const int*   adj_rows = (const int*)d_in[3];
  const int*   adj_cols = (const int*)d_in[4];
  const float* adj_vals = (const float*)d_in[5];
  const float* Eu0      = (const float*)d_in[6];
  const float* Ei0      = (const float*)d_in[7];
  const float* umuls    = (const float*)d_in[8];
  const float* vt       = (const float*)d_in[9];
  const float* vmuls    = (const float*)d_in[10];
  const float* ut       = (const float*)d_in[11];
  const float* W_api    = (const float*)d_in[12];
  const float* b_api    = (const float*)d_in[13];
  const float* W_mash   = (const float*)d_in[14];
  const float* b_mash   = (const float*)d_in[15];
  const float* pos_api  = (const float*)d_in[16];
  const float* neg_api  = (const float*)d_in[17];
  const float* mashup   = (const float*)d_in[18];
  const int*   unpop    = (const int*)d_in[19];
  const int*   popi     = (const int*)d_in[20];

  float* out = (float*)d_out;
  float* ws  = (float*)d_ws;
  int*   wsi = (int*)d_ws;

  float* Z_i1   = ws + WS_ZI1;
  int*   counts = wsi + WS_CNT;
  int*   offs   = wsi + WS_OFFS;
  int*   cursor = wsi + WS_CUR;
  int*   bsum   = wsi + WS_BSUM;
  int2*  pairs  = (int2*)(wsi + WS_PAIRS);
  float* T_i    = ws + WS_TI;
  float* T_u    = ws + WS_TU;
  float* Gb     = ws + WS_GB;
  float* s_u    = ws + WS_SU;
  float* s_i    = ws + WS_SI;
  float* acc    = ws + WS_ACC;
  unsigned short* Gb16  = (unsigned short*)(wsi + WS_GB16);
  unsigned short* EuB16 = (unsigned short*)(wsi + WS_ZI1);    // overlays Z_i1 (free after layer 2)
  unsigned short* EiB16 = (unsigned short*)(wsi + WS_PAIRS);  // overlays pairs (free after layer 2)

  // out layout: [0..3) scalars, then mashup/pos_api/neg_api, then E_u, E_i
  float* Eu_out = out + 1179651;   // also holds Z_u1 between layer 1 and layer 2
  float* Ei_out = out + 7579651;

  hipMemsetAsync(counts, 0, 150001ull * 4ull, stream);
  hipMemsetAsync(T_i, 0, (size_t)WS_SMALL_LEN * 4ull, stream);

  const int NROWS = N_U + N_I;                  // 150000
  const int SCAN_BLKS = (NROWS + 1023) / 1024;  // 147

  hist_kernel<<<(NNZ_N + 255) / 256, 256, 0, stream>>>(adj_rows, adj_cols, counts);
  scan1_kernel<<<SCAN_BLKS, 256, 0, stream>>>(counts, bsum, NROWS);
  scan2_kernel<<<1, 256, 0, stream>>>(bsum, SCAN_BLKS);
  scan3_kernel<<<SCAN_BLKS, 256, 0, stream>>>(counts, bsum, offs, cursor, NROWS);
  scatter_bucketed<<<8 * SC_K, 256, 0, stream>>>(adj_rows, adj_cols, adj_vals, cursor, pairs);

  // layer 1: Z_u1 = A @ Ei0 (stored in Eu_out), Z_i1 = A^T @ Eu0 (ws)
  spmm_gather<<<25000, 256, 0, stream>>>(offs, pairs, Ei0, nullptr, nullptr, Eu_out, N_U);
  spmm_gather<<<12500, 256, 0, stream>>>(offs + N_U, pairs, Eu0, nullptr, nullptr, Z_i1, N_I);

  calcT_kernel<<<256, 256, 0, stream>>>(vt, Ei0, Z_i1, T_i, N_I);
  calcT_kernel<<<256, 256, 0, stream>>>(ut, Eu0, Eu_out, T_u, N_U);
  calcG_kernel<<<384, 256, 0, stream>>>(uids, pos, neg, Eu0, Ei0, umuls, vmuls, T_i, T_u, Gb);

  // layer 2 (i first: reads Z_u1 from Eu_out before it is overwritten)
  spmm_gather<<<12500, 256, 0, stream>>>(offs + N_U, pairs, Eu_out, Ei0, Z_i1, Ei_out, N_I);
  spmm_gather<<<25000, 256, 0, stream>>>(offs, pairs, Z_i1, Eu0, Eu_out, Eu_out, N_U);

  // bf16 copies for the MFMA logits (overlay regions now free)
  cvt_bf16_kernel<<<(N_U * DD / 4 + 255) / 256, 256, 0, stream>>>(Eu_out, EuB16, N_U * DD / 4);
  cvt_bf16_kernel<<<(N_I * DD / 4 + 255) / 256, 256, 0, stream>>>(Ei_out, EiB16, N_I * DD / 4);
  cvt_bf16_kernel<<<(1536 * DD / 4 + 255) / 256, 256, 0, stream>>>(Gb, Gb16, 1536 * DD / 4);

  // contrastive exp-sums via MFMA
  logits_mfma<<<dim3(64, 4), 256, 0, stream>>>(Gb16, EuB16, N_U, s_u);
  logits_mfma<<<dim3(32, 8), 256, 0, stream>>>(Gb16 + 512 * DD, EiB16, N_I, s_i);

  small_losses_kernel<<<512, 256, 0, stream>>>(uids, pos, neg, Gb, Eu_out, Ei_out, acc);
  sq_kernel<<<1024, 256, 0, stream>>>(Eu0, Ei0, W_api, b_api, W_mash, b_mash, acc + 3);
  extra_kernel<<<64, 256, 0, stream>>>(unpop, popi, Ei_out, acc + 4);
  finalize_kernel<<<1, 1024, 0, stream>>>(s_u, s_i, acc, out);
  copy3_kernel<<<1536, 256, 0, stream>>>(mashup, pos_api, neg_api, out);
  (void)in_sizes; (void)n_in; (void)out_size; (void)ws_size;
}

// Round 7
// 751.893 us; speedup vs baseline: 6.5901x; 1.0842x over previous
//
#include <hip/hip_runtime.h>
#include <math.h>

#define N_U 100000
#define N_I 50000
#define DD 64
#define NQ 5
#define NNZ_N 1000000
#define NB 512
#define IN_DIM 768
#define TEMP 0.2f
// (1/TEMP) * log2(e)
#define SCALE2 7.2134752044448169f

// ws dword offsets
#define WS_ZI1   0          // 3,200,000 f  (Z_i1; later reused as EuB16)
#define WS_CNT   3200000    // 150,001 int
#define WS_OFFS  3350016    // 150,001 int
#define WS_CUR   3500032    // 150,000 int
#define WS_BSUM  3650048    // 256 int
#define WS_PAIRS 3650304    // 4,000,000 dwords (2M int2; later reused as EiB16)
#define WS_TI    7650304    // 320 f
#define WS_TU    7650624    // 320 f
#define WS_GB    7650944    // 98,304 f
#define WS_SU    7749248    // 512 f
#define WS_SI    7749760    // 1024 f
#define WS_ACC   7750784    // 8 f
#define WS_SMALL_LEN (7750792 - WS_TI)
#define WS_GB16  7750792    // 49,152 dwords (1536*64 bf16)

typedef short short8 __attribute__((ext_vector_type(8)));
typedef float float4v __attribute__((ext_vector_type(4)));
typedef int   int4v   __attribute__((ext_vector_type(4)));

__device__ __forceinline__ float wave_red_sum(float v) {
#pragma unroll
  for (int m = 32; m >= 1; m >>= 1) v += __shfl_xor(v, m, 64);
  return v;
}

__device__ __forceinline__ unsigned short f2bf(float f) {
  unsigned u = __float_as_uint(f);
  unsigned r = (u + 0x7fffu + ((u >> 16) & 1u)) >> 16;
  return (unsigned short)r;
}

// ---------------- CSR/CSC build ----------------

__global__ void hist_kernel(const int* __restrict__ rows, const int* __restrict__ cols,
                            int* __restrict__ counts) {
  int e = blockIdx.x * 256 + threadIdx.x;
  if (e >= NNZ_N) return;
  atomicAdd(&counts[rows[e]], 1);
  atomicAdd(&counts[N_U + cols[e]], 1);
}

__global__ void scan1_kernel(const int* __restrict__ counts, int* __restrict__ bsum, int n) {
  int t = threadIdx.x;
  int base = blockIdx.x * 1024 + t * 4;
  int s = 0;
#pragma unroll
  for (int k = 0; k < 4; k++) { int i = base + k; if (i < n) s += counts[i]; }
#pragma unroll
  for (int m = 32; m >= 1; m >>= 1) s += __shfl_xor(s, m, 64);
  __shared__ int sw[4];
  if ((t & 63) == 0) sw[t >> 6] = s;
  __syncthreads();
  if (t == 0) bsum[blockIdx.x] = sw[0] + sw[1] + sw[2] + sw[3];
}

__global__ void scan2_kernel(int* __restrict__ bsum, int nb) {
  int t = threadIdx.x;
  int lane = t & 63, w = t >> 6;
  int orig = (t < nb) ? bsum[t] : 0;
  int v = orig;
#pragma unroll
  for (int m = 1; m < 64; m <<= 1) { int o = __shfl_up(v, m, 64); if (lane >= m) v += o; }
  __shared__ int wt[4];
  if (lane == 63) wt[w] = v;
  __syncthreads();
  int add = 0;
  for (int k = 0; k < w; k++) add += wt[k];
  if (t < nb) bsum[t] = v - orig + add;
}

__global__ void scan3_kernel(const int* __restrict__ counts, const int* __restrict__ bsum,
                             int* __restrict__ offs, int* __restrict__ cursor, int n) {
  int t = threadIdx.x;
  int lane = t & 63, w = t >> 6;
  int base = blockIdx.x * 1024 + t * 4;
  int c[4];
  int s = 0;
#pragma unroll
  for (int k = 0; k < 4; k++) { int i = base + k; c[k] = (i < n) ? counts[i] : 0; s += c[k]; }
  int v = s;
#pragma unroll
  for (int m = 1; m < 64; m <<= 1) { int o = __shfl_up(v, m, 64); if (lane >= m) v += o; }
  __shared__ int wt[4];
  if (lane == 63) wt[w] = v;
  __syncthreads();
  int add = bsum[blockIdx.x];
  for (int k = 0; k < w; k++) add += wt[k];
  int excl = add + v - s;
#pragma unroll
  for (int k = 0; k < 4; k++) {
    int i = base + k;
    if (i < n) {
      offs[i] = excl;
      cursor[i] = excl;
      if (i == n - 1) offs[n] = excl + c[k];
      excl += c[k];
    }
  }
}

// Bucketed scatter with 4-edge ILP. 8 destination buckets (XCD affinity via %8),
// SC_K slices per bucket; each iteration loads 4 edges via vector non-temporal
// loads and issues up to 4 independent atomic+store chains.
#define SC_K 384
__global__ void scatter_bucketed(const int* __restrict__ rows, const int* __restrict__ cols,
                                 const float* __restrict__ vals, int* __restrict__ cursor,
                                 int2* __restrict__ pairs) {
  int b = blockIdx.x & 7;
  int slice = blockIdx.x >> 3;
  const int stride = SC_K * 256;
  bool uside = (b < 4);
  int lo = uside ? b * 25000 : (b - 4) * 12500;
  int hi = uside ? lo + 25000 : lo + 12500;
  const int nquad = NNZ_N / 4;
  for (int q = slice * 256 + threadIdx.x; q < nquad; q += stride) {
    int4v r4 = __builtin_nontemporal_load((const int4v*)rows + q);
    int4v c4 = __builtin_nontemporal_load((const int4v*)cols + q);
    float4v v4 = __builtin_nontemporal_load((const float4v*)vals + q);
    int rr[4] = {r4.x, r4.y, r4.z, r4.w};
    int cc[4] = {c4.x, c4.y, c4.z, c4.w};
    float vv[4] = {v4.x, v4.y, v4.z, v4.w};
#pragma unroll
    for (int k = 0; k < 4; k++) {
      if (uside) {
        if (rr[k] >= lo && rr[k] < hi) {
          int s1 = atomicAdd(&cursor[rr[k]], 1);
          pairs[s1] = make_int2(cc[k], __float_as_int(vv[k]));
        }
      } else {
        if (cc[k] >= lo && cc[k] < hi) {
          int s2 = atomicAdd(&cursor[N_U + cc[k]], 1);
          pairs[s2] = make_int2(rr[k], __float_as_int(vv[k]));
        }
      }
    }
  }
}

// ---------------- gather SpMM ----------------

__device__ __forceinline__ void spmm_row(const int* __restrict__ offs,
                                         const int2* __restrict__ pairs,
                                         const float* __restrict__ src,
                                         const float* __restrict__ base0,
                                         const float* __restrict__ base1,
                                         float* __restrict__ dst, int row, int lane) {
  int s = offs[row], e = offs[row + 1];
  float acc = 0.f;
  int k = s;
  for (; k + 4 <= e; k += 4) {
    int2 p0 = pairs[k + 0];
    int2 p1 = pairs[k + 1];
    int2 p2 = pairs[k + 2];
    int2 p3 = pairs[k + 3];
    float x0 = src[(size_t)p0.x * DD + lane];
    float x1 = src[(size_t)p1.x * DD + lane];
    float x2 = src[(size_t)p2.x * DD + lane];
    float x3 = src[(size_t)p3.x * DD + lane];
    acc += __int_as_float(p0.y) * x0;
    acc += __int_as_float(p1.y) * x1;
    acc += __int_as_float(p2.y) * x2;
    acc += __int_as_float(p3.y) * x3;
  }
  for (; k < e; k++) {
    int2 p = pairs[k];
    acc += __int_as_float(p.y) * src[(size_t)p.x * DD + lane];
  }
  if (base0) acc += base0[(size_t)row * DD + lane];
  if (base1) acc += base1[(size_t)row * DD + lane];
  dst[(size_t)row * DD + lane] = acc;
}

__global__ void spmm_gather(const int* __restrict__ offs, const int2* __restrict__ pairs,
                            const float* __restrict__ src, const float* __restrict__ base0,
                            const float* __restrict__ base1, float* __restrict__ dst,
                            int n_rows) {
  int gid = blockIdx.x * 256 + threadIdx.x;
  int row = gid >> 6, lane = gid & 63;
  if (row >= n_rows) return;
  spmm_row(offs, pairs, src, base0, base1, dst, row, lane);
}

// fused layer 1: Z_u1 = A @ Ei0 (-> Eu_out), Z_i1 = A^T @ Eu0 (-> ws)
__global__ void spmm_layer1(const int* __restrict__ offs, const int2* __restrict__ pairs,
                            const float* __restrict__ Eu0, const float* __restrict__ Ei0,
                            float* __restrict__ Zu1, float* __restrict__ Zi1) {
  int bid = blockIdx.x;
  int lane = threadIdx.x & 63;
  int sub = threadIdx.x >> 6;
  if (bid < 25000) {
    int row = bid * 4 + sub;
    spmm_row(offs, pairs, Ei0, nullptr, nullptr, Zu1, row, lane);
  } else {
    int row = (bid - 25000) * 4 + sub;
    spmm_row(offs + N_U, pairs, Eu0, nullptr, nullptr, Zi1, row, lane);
  }
}

// ---------------- SVD low-rank path ----------------

// y=0: T_i = vt @ (Ei0 + Zi1); y=1: T_u = ut @ (Eu0 + Zu1)
__global__ void calcT_fused(const float* __restrict__ vt, const float* __restrict__ ut,
                            const float* __restrict__ Ei0, const float* __restrict__ Zi1,
                            const float* __restrict__ Eu0, const float* __restrict__ Zu1,
                            float* __restrict__ Ti, float* __restrict__ Tu) {
  const float* V; const float* A; const float* B; float* T; int N;
  if (blockIdx.y == 0) { V = vt; A = Ei0; B = Zi1; T = Ti; N = N_I; }
  else                 { V = ut; A = Eu0; B = Zu1; T = Tu; N = N_U; }
  int lane = threadIdx.x & 63;
  int wave = (blockIdx.x * blockDim.x + threadIdx.x) >> 6;
  int nw = (gridDim.x * blockDim.x) >> 6;
  float a0 = 0.f, a1 = 0.f, a2 = 0.f, a3 = 0.f, a4 = 0.f;
  for (int j = wave; j < N; j += nw) {
    float x = A[(size_t)j * DD + lane] + B[(size_t)j * DD + lane];
    a0 += V[0 * N + j] * x;
    a1 += V[1 * N + j] * x;
    a2 += V[2 * N + j] * x;
    a3 += V[3 * N + j] * x;
    a4 += V[4 * N + j] * x;
  }
  atomicAdd(&T[0 * DD + lane], a0);
  atomicAdd(&T[1 * DD + lane], a1);
  atomicAdd(&T[2 * DD + lane], a2);
  atomicAdd(&T[3 * DD + lane], a3);
  atomicAdd(&T[4 * DD + lane], a4);
}

__global__ void calcG_kernel(const int* __restrict__ uids, const int* __restrict__ pos,
                             const int* __restrict__ neg,
                             const float* __restrict__ Eu0, const float* __restrict__ Ei0,
                             const float* __restrict__ umuls, const float* __restrict__ vmuls,
                             const float* __restrict__ Ti, const float* __restrict__ Tu,
                             float* __restrict__ Gb) {
  int gid = blockIdx.x * 256 + threadIdx.x;
  if (gid >= 1536 * DD) return;
  int rrow = gid >> 6, d = gid & 63;
  float g;
  if (rrow < 512) {
    int u = uids[rrow];
    g = Eu0[(size_t)u * DD + d];
#pragma unroll
    for (int q = 0; q < NQ; q++) g += umuls[u * NQ + q] * Ti[q * DD + d];
  } else {
    int rr = rrow - 512;
    int i = (rr < 512) ? pos[rr] : neg[rr - 512];
    g = Ei0[(size_t)i * DD + d];
#pragma unroll
    for (int q = 0; q < NQ; q++) g += vmuls[i * NQ + q] * Tu[q * DD + d];
  }
  Gb[gid] = g;
}

// fused fp32 -> bf16 converts: Eu (1.6M float4), Ei (800K float4), Gb (24576 float4)
#define CV_NU4 (N_U * DD / 4)
#define CV_NI4 (N_I * DD / 4)
#define CV_NG4 (1536 * DD / 4)
__global__ void cvt_fused(const float* __restrict__ Eu, const float* __restrict__ Ei,
                          const float* __restrict__ Gb, unsigned short* __restrict__ EuB,
                          unsigned short* __restrict__ EiB, unsigned short* __restrict__ GbB) {
  int i = blockIdx.x * 256 + threadIdx.x;
  const float* in; unsigned short* op; int k;
  if (i < CV_NU4) { in = Eu; op = EuB; k = i; }
  else if (i < CV_NU4 + CV_NI4) { in = Ei; op = EiB; k = i - CV_NU4; }
  else if (i < CV_NU4 + CV_NI4 + CV_NG4) { in = Gb; op = GbB; k = i - CV_NU4 - CV_NI4; }
  else return;
  float4 x = *(const float4*)(in + (size_t)k * 4);
  ushort4 o;
  o.x = f2bf(x.x); o.y = f2bf(x.y); o.z = f2bf(x.z); o.w = f2bf(x.w);
  *(ushort4*)(op + (size_t)k * 4) = o;
}

// ---------------- contrastive exp-sums via MFMA ----------------
#define GPB 8
__global__ __launch_bounds__(256) void logits_mfma(
    const unsigned short* __restrict__ Gb16, const unsigned short* __restrict__ Eb16,
    int N, float* __restrict__ s_out) {
  int tid = threadIdx.x;
  int lane = tid & 63;
  int wave = tid >> 6;
  int col = lane & 15;
  int quad = lane >> 4;
  int gbase = blockIdx.y * (GPB * 16);

  short8 afrag[GPB][2];
#pragma unroll
  for (int gg = 0; gg < GPB; gg++) {
    const unsigned short* gp = Gb16 + (size_t)(gbase + gg * 16 + col) * 64 + quad * 8;
    afrag[gg][0] = *(const short8*)(gp);
    afrag[gg][1] = *(const short8*)(gp + 32);
  }

  float psum[GPB][4];
#pragma unroll
  for (int gg = 0; gg < GPB; gg++)
#pragma unroll
    for (int r = 0; r < 4; r++) psum[gg][r] = 0.f;

  int nt = N >> 4;
  int wid = blockIdx.x * 4 + wave;
  int nw = gridDim.x * 4;
  for (int t = wid; t < nt; t += nw) {
    const unsigned short* ep = Eb16 + (size_t)(t * 16 + col) * 64 + quad * 8;
    short8 b0 = *(const short8*)(ep);
    short8 b1 = *(const short8*)(ep + 32);
#pragma unroll
    for (int gg = 0; gg < GPB; gg++) {
      float4v acc = {0.f, 0.f, 0.f, 0.f};
      acc = __builtin_amdgcn_mfma_f32_16x16x32_bf16(afrag[gg][0], b0, acc, 0, 0, 0);
      acc = __builtin_amdgcn_mfma_f32_16x16x32_bf16(afrag[gg][1], b1, acc, 0, 0, 0);
#pragma unroll
      for (int r = 0; r < 4; r++) psum[gg][r] += exp2f(acc[r] * SCALE2);
    }
  }
#pragma unroll
  for (int gg = 0; gg < GPB; gg++)
#pragma unroll
    for (int r = 0; r < 4; r++) {
      float v = psum[gg][r];
#pragma unroll
      for (int m = 1; m <= 8; m <<= 1) v += __shfl_xor(v, m, 64);
      psum[gg][r] = v;
    }
  if (col == 0) {
#pragma unroll
    for (int gg = 0; gg < GPB; gg++)
#pragma unroll
      for (int r = 0; r < 4; r++)
        atomicAdd(&s_out[gbase + gg * 16 + quad * 4 + r], psum[gg][r]);
  }
}

// ---------------- fused tail: copy3 | sq | small_losses | extra ----------------
// blocks [0,1536): copy3; [1536,2560): sq; [2560,3072): small_losses; [3072,3136): extra
__global__ void tail_kernel(const float* __restrict__ m, const float* __restrict__ pa,
                            const float* __restrict__ na,
                            const float* __restrict__ p0, const float* __restrict__ p1,
                            const float* __restrict__ p2, const float* __restrict__ p3,
                            const float* __restrict__ p4, const float* __restrict__ p5,
                            const int* __restrict__ uids, const int* __restrict__ pos,
                            const int* __restrict__ neg, const float* __restrict__ Gb,
                            const float* __restrict__ Eu, const float* __restrict__ Ei,
                            const int* __restrict__ unpop, const int* __restrict__ pop,
                            float* __restrict__ out, float* __restrict__ acc) {
  int bid = blockIdx.x;
  int t = threadIdx.x;
  __shared__ float sw[4];
  if (bid < 1536) {
    int i = bid * 256 + t;
    if (i < NB * IN_DIM) {
      out[3 + i] = m[i];
      out[3 + NB * IN_DIM + i] = pa[i];
      out[3 + 2 * NB * IN_DIM + i] = na[i];
    }
    return;
  }
  if (bid < 2560) {
    int lb = bid - 1536;  // 1024 blocks
    const int n0 = N_U * DD, n1 = N_I * DD, n2 = IN_DIM * DD, n3 = DD, n4 = IN_DIM * DD, n5 = DD;
    const int total = n0 + n1 + n2 + n3 + n4 + n5;
    float s = 0.f;
    for (int i = lb * 256 + t; i < total; i += 1024 * 256) {
      int k = i; float v;
      if (k < n0) v = p0[k];
      else { k -= n0; if (k < n1) v = p1[k];
        else { k -= n1; if (k < n2) v = p2[k];
          else { k -= n2; if (k < n3) v = p3[k];
            else { k -= n3; if (k < n4) v = p4[k];
              else { k -= n4; v = p5[k]; } } } } }
      s += v * v;
    }
    s = wave_red_sum(s);
    int lane = t & 63, w = t >> 6;
    if (lane == 0) sw[w] = s;
    __syncthreads();
    if (t == 0) atomicAdd(&acc[3], sw[0] + sw[1] + sw[2] + sw[3]);
    return;
  }
  if (bid < 3072) {
    int lb = bid - 2560;  // 512 blocks
    int wid = (lb * 256 + t) >> 6;
    int lane = t & 63;
    if (wid < 512) {
      int u = uids[wid];
      float p = Gb[(size_t)wid * DD + lane] * Eu[(size_t)u * DD + lane];
      p = wave_red_sum(p);
      if (lane == 0) atomicAdd(&acc[0], fminf(fmaxf(p * (1.0f / TEMP), -5.0f), 5.0f));
    } else if (wid < 1536) {
      int r = wid - 512;
      int i = (r < 512) ? pos[r] : neg[r - 512];
      float p = Gb[(size_t)wid * DD + lane] * Ei[(size_t)i * DD + lane];
      p = wave_red_sum(p);
      if (lane == 0) atomicAdd(&acc[1], fminf(fmaxf(p * (1.0f / TEMP), -5.0f), 5.0f));
    } else {
      int b = wid - 1536;
      int u = uids[b], ip = pos[b], in2 = neg[b];
      float eu = Eu[(size_t)u * DD + lane];
      float sp = wave_red_sum(eu * Ei[(size_t)ip * DD + lane]);
      float sn = wave_red_sum(eu * Ei[(size_t)in2 * DD + lane]);
      if (lane == 0) {
        float x = sp - sn;
        float ls = fminf(x, 0.0f) - log1pf(expf(-fabsf(x)));
        atomicAdd(&acc[2], ls);
      }
    }
    return;
  }
  {
    int blk = bid - 3072;  // 64 blocks
    int q = t >> 5, p = t & 31;
    int ui = unpop[blk * 8 + q];
    int pi = pop[blk * 32 + p];
    float s = 0.f;
#pragma unroll
    for (int d = 0; d < DD; d++) {
      float df = Ei[(size_t)ui * DD + d] - Ei[(size_t)pi * DD + d];
      s += df * df;
    }
    float dist = sqrtf(s);
    dist = wave_red_sum(dist);
    int lane = t & 63, w = t >> 6;
    if (lane == 0) sw[w] = dist;
    __syncthreads();
    if (t == 0) atomicAdd(&acc[4], (sw[0] + sw[1] + sw[2] + sw[3]) * (1.0f / 32.0f));
  }
}

__global__ void finalize_kernel(const float* __restrict__ s_u, const float* __restrict__ s_i,
                                const float* __restrict__ acc, float* __restrict__ out) {
  int tid = threadIdx.x;  // 1024
  float lu = (tid < 512) ? logf(s_u[tid] + 1e-8f) : 0.f;
  float li = logf(s_i[tid] + 1e-8f);
  lu = wave_red_sum(lu);
  li = wave_red_sum(li);
  __shared__ float sa[16], sb[16];
  int lane = tid & 63, w = tid >> 6;
  if (lane == 0) { sa[w] = lu; sb[w] = li; }
  __syncthreads();
  if (tid == 0) {
    float su = 0.f, si = 0.f;
    for (int k = 0; k < 16; k++) { su += sa[k]; si += sb[k]; }
    float neg_score = su / 512.0f + si / 1024.0f;
    float pos_score = acc[0] / 512.0f + acc[1] / 1024.0f;
    float loss_s = neg_score - pos_score;
    float loss_r = -acc[2] / 512.0f;
    float loss_reg = 1e-7f * acc[3];
    float extra = acc[4];
    float loss = loss_r + 0.2f * loss_s + loss_reg + 0.01f * extra;
    out[0] = loss;
    out[1] = loss_r;
    out[2] = 0.2f * loss_s;
  }
}

extern "C" void kernel_launch(void* const* d_in, const int* in_sizes, int n_in,
                              void* d_out, int out_size, void* d_ws, size_t ws_size,
                              hipStream_t stream) {
  const int*   uids     = (const int*)d_in[0];
  const int*   pos      = (const int*)d_in[1];
  const int*   neg      = (const int*)d_in[2];
  const int*   adj_rows = (const int*)d_in[3];
  const int*   adj_cols = (const int*)d_in[4];
  const float* adj_vals = (const float*)d_in[5];
  const float* Eu0      = (const float*)d_in[6];
  const float* Ei0      = (const float*)d_in[7];
  const float* umuls    = (const float*)d_in[8];
  const float* vt       = (const float*)d_in[9];
  const float* vmuls    = (const float*)d_in[10];
  const float* ut       = (const float*)d_in[11];
  const float* W_api    = (const float*)d_in[12];
  const float* b_api    = (const float*)d_in[13];
  const float* W_mash   = (const float*)d_in[14];
  const float* b_mash   = (const float*)d_in[15];
  const float* pos_api  = (const float*)d_in[16];
  const float* neg_api  = (const float*)d_in[17];
  const float* mashup   = (const float*)d_in[18];
  const int*   unpop    = (const int*)d_in[19];
  const int*   popi     = (const int*)d_in[20];

  float* out = (float*)d_out;
  float* ws  = (float*)d_ws;
  int*   wsi = (int*)d_ws;

  float* Z_i1   = ws + WS_ZI1;
  int*   counts = wsi + WS_CNT;
  int*   offs   = wsi + WS_OFFS;
  int*   cursor = wsi + WS_CUR;
  int*   bsum   = wsi + WS_BSUM;
  int2*  pairs  = (int2*)(wsi + WS_PAIRS);
  float* T_i    = ws + WS_TI;
  float* T_u    = ws + WS_TU;
  float* Gb     = ws + WS_GB;
  float* s_u    = ws + WS_SU;
  float* s_i    = ws + WS_SI;
  float* acc    = ws + WS_ACC;
  unsigned short* Gb16  = (unsigned short*)(wsi + WS_GB16);
  unsigned short* EuB16 = (unsigned short*)(wsi + WS_ZI1);    // overlays Z_i1 (free after layer 2)
  unsigned short* EiB16 = (unsigned short*)(wsi + WS_PAIRS);  // overlays pairs (free after layer 2)

  // out layout: [0..3) scalars, then mashup/pos_api/neg_api, then E_u, E_i
  float* Eu_out = out + 1179651;   // also holds Z_u1 between layer 1 and layer 2
  float* Ei_out = out + 7579651;

  hipMemsetAsync(counts, 0, 150001ull * 4ull, stream);
  hipMemsetAsync(T_i, 0, (size_t)WS_SMALL_LEN * 4ull, stream);

  const int NROWS = N_U + N_I;                  // 150000
  const int SCAN_BLKS = (NROWS + 1023) / 1024;  // 147

  hist_kernel<<<(NNZ_N + 255) / 256, 256, 0, stream>>>(adj_rows, adj_cols, counts);
  scan1_kernel<<<SCAN_BLKS, 256, 0, stream>>>(counts, bsum, NROWS);
  scan2_kernel<<<1, 256, 0, stream>>>(bsum, SCAN_BLKS);
  scan3_kernel<<<SCAN_BLKS, 256, 0, stream>>>(counts, bsum, offs, cursor, NROWS);
  scatter_bucketed<<<8 * SC_K, 256, 0, stream>>>(adj_rows, adj_cols, adj_vals, cursor, pairs);

  // fused layer 1: Z_u1 -> Eu_out, Z_i1 -> ws
  spmm_layer1<<<37500, 256, 0, stream>>>(offs, pairs, Eu0, Ei0, Eu_out, Z_i1);

  calcT_fused<<<dim3(256, 2), 256, 0, stream>>>(vt, ut, Ei0, Z_i1, Eu0, Eu_out, T_i, T_u);
  calcG_kernel<<<384, 256, 0, stream>>>(uids, pos, neg, Eu0, Ei0, umuls, vmuls, T_i, T_u, Gb);

  // layer 2 (i first: reads Z_u1 from Eu_out before it is overwritten)
  spmm_gather<<<12500, 256, 0, stream>>>(offs + N_U, pairs, Eu_out, Ei0, Z_i1, Ei_out, N_I);
  spmm_gather<<<25000, 256, 0, stream>>>(offs, pairs, Z_i1, Eu0, Eu_out, Eu_out, N_U);

  // fused bf16 converts (overlay regions now free)
  cvt_fused<<<(CV_NU4 + CV_NI4 + CV_NG4 + 255) / 256, 256, 0, stream>>>(
      Eu_out, Ei_out, Gb, EuB16, EiB16, Gb16);

  // contrastive exp-sums via MFMA
  logits_mfma<<<dim3(64, 4), 256, 0, stream>>>(Gb16, EuB16, N_U, s_u);
  logits_mfma<<<dim3(32, 8), 256, 0, stream>>>(Gb16 + 512 * DD, EiB16, N_I, s_i);

  // fused tail: copy3 | sq | small_losses | extra
  tail_kernel<<<3136, 256, 0, stream>>>(mashup, pos_api, neg_api,
                                        Eu0, Ei0, W_api, b_api, W_mash, b_mash,
                                        uids, pos, neg, Gb, Eu_out, Ei_out,
                                        unpop, popi, out, acc);
  finalize_kernel<<<1, 1024, 0, stream>>>(s_u, s_i, acc, out);
  (void)in_sizes; (void)n_in; (void)out_size; (void)ws_size;
}